// Round 1
// baseline (31585.468 us; speedup 1.0000x reference)
//
#include <hip/hip_runtime.h>
#include <hip/hip_bf16.h>
#include <math.h>

// Problem constants
#define BB 2
#define TT 2048
#define DD 512
#define HH 8
#define HD 64
#define FF 2048
#define VV 32000
#define LL 6
#define MM (BB * TT)   // 4096

// ---------------------------------------------------------------------------
// Embedding: x[b,t,:] = wte[idx[b,t],:] + wpe[t,:]
// grid = M blocks, 128 threads, float4 per thread (D=512 = 128*4)
// ---------------------------------------------------------------------------
__global__ __launch_bounds__(128)
void embed_kernel(const int* __restrict__ idx, const float* __restrict__ wte,
                  const float* __restrict__ wpe, float* __restrict__ x)
{
    int row = blockIdx.x;            // b*T + t
    int t = row & (TT - 1);
    int tok = idx[row];
    const float4* wt = (const float4*)(wte + (size_t)tok * DD);
    const float4* wp = (const float4*)(wpe + (size_t)t * DD);
    float4 a = wt[threadIdx.x];
    float4 p = wp[threadIdx.x];
    float4 r;
    r.x = a.x + p.x; r.y = a.y + p.y; r.z = a.z + p.z; r.w = a.w + p.w;
    ((float4*)(x + (size_t)row * DD))[threadIdx.x] = r;
}

// ---------------------------------------------------------------------------
// LayerNorm over rows of length 512. 1 block (256 threads) per row.
// ---------------------------------------------------------------------------
__global__ __launch_bounds__(256)
void ln_kernel(const float* __restrict__ x, const float* __restrict__ g,
               const float* __restrict__ b, float* __restrict__ out)
{
    int row = blockIdx.x;
    const float* xr = x + (size_t)row * DD;
    int tid = threadIdx.x;
    float v1 = xr[tid], v2 = xr[tid + 256];
    float s = v1 + v2;
    float ss = v1 * v1 + v2 * v2;
    #pragma unroll
    for (int o = 32; o; o >>= 1) {
        s  += __shfl_xor(s, o);
        ss += __shfl_xor(ss, o);
    }
    __shared__ float sred[4], ssred[4];
    int wid = tid >> 6, lane = tid & 63;
    if (lane == 0) { sred[wid] = s; ssred[wid] = ss; }
    __syncthreads();
    s  = sred[0] + sred[1] + sred[2] + sred[3];
    ss = ssred[0] + ssred[1] + ssred[2] + ssred[3];
    float mu  = s * (1.0f / DD);
    float var = ss * (1.0f / DD) - mu * mu;
    float rs  = rsqrtf(var + 1e-5f);
    float* orow = out + (size_t)row * DD;
    orow[tid]       = (v1 - mu) * rs * g[tid]       + b[tid];
    orow[tid + 256] = (v2 - mu) * rs * g[tid + 256] + b[tid + 256];
}

// ---------------------------------------------------------------------------
// fp32 GEMM: C[M,N] = epilogue(A[M,K] @ B + bias)
//   TRANSB=false: B is [K,N] row-major.  TRANSB=true: B is [N,K] row-major.
//   GELU_ACT: exact erf GELU.  RESID: C = resid + result.
// 64x64 tile, BK=16, 256 threads, 4x4 per thread. M,N,K all % 64/16 here.
// ---------------------------------------------------------------------------
__device__ __forceinline__ float gelu_exact(float v)
{
    return 0.5f * v * (1.0f + erff(v * 0.70710678118654752440f));
}

template<bool TRANSB, bool GELU_ACT, bool RESID>
__global__ __launch_bounds__(256)
void gemm_kernel(const float* __restrict__ A, const float* __restrict__ Bmat,
                 const float* __restrict__ bias, const float* __restrict__ resid,
                 float* __restrict__ C, int M, int N, int K)
{
    __shared__ float As[64][17];      // +1 pad: kills 4-way conflict on A reads
    __shared__ float Bs[16][64];      // !TRANSB path (float4-aligned rows)
    __shared__ float BsT[64][17];     // TRANSB path (n-major, padded)

    int tid = threadIdx.x;
    int tx = tid & 15, ty = tid >> 4;
    int m0 = blockIdx.y * 64, n0 = blockIdx.x * 64;

    float acc[4][4] = {};

    int ar = tid >> 2, ac = (tid & 3) * 4;       // A / BsT staging indices
    int br = tid >> 4, bc = (tid & 15) * 4;      // Bs staging indices

    for (int k0 = 0; k0 < K; k0 += 16) {
        float4 av = *(const float4*)(A + (size_t)(m0 + ar) * K + k0 + ac);
        As[ar][ac + 0] = av.x; As[ar][ac + 1] = av.y;
        As[ar][ac + 2] = av.z; As[ar][ac + 3] = av.w;
        if constexpr (!TRANSB) {
            float4 bv = *(const float4*)(Bmat + (size_t)(k0 + br) * N + n0 + bc);
            *(float4*)&Bs[br][bc] = bv;
        } else {
            float4 bv = *(const float4*)(Bmat + (size_t)(n0 + ar) * K + k0 + ac);
            BsT[ar][ac + 0] = bv.x; BsT[ar][ac + 1] = bv.y;
            BsT[ar][ac + 2] = bv.z; BsT[ar][ac + 3] = bv.w;
        }
        __syncthreads();
        #pragma unroll
        for (int kk = 0; kk < 16; ++kk) {
            float a0 = As[ty * 4 + 0][kk];
            float a1 = As[ty * 4 + 1][kk];
            float a2 = As[ty * 4 + 2][kk];
            float a3 = As[ty * 4 + 3][kk];
            float b0, b1, b2, b3;
            if constexpr (!TRANSB) {
                float4 bv = *(const float4*)&Bs[kk][tx * 4];
                b0 = bv.x; b1 = bv.y; b2 = bv.z; b3 = bv.w;
            } else {
                b0 = BsT[tx * 4 + 0][kk];
                b1 = BsT[tx * 4 + 1][kk];
                b2 = BsT[tx * 4 + 2][kk];
                b3 = BsT[tx * 4 + 3][kk];
            }
            acc[0][0] += a0 * b0; acc[0][1] += a0 * b1; acc[0][2] += a0 * b2; acc[0][3] += a0 * b3;
            acc[1][0] += a1 * b0; acc[1][1] += a1 * b1; acc[1][2] += a1 * b2; acc[1][3] += a1 * b3;
            acc[2][0] += a2 * b0; acc[2][1] += a2 * b1; acc[2][2] += a2 * b2; acc[2][3] += a2 * b3;
            acc[3][0] += a3 * b0; acc[3][1] += a3 * b1; acc[3][2] += a3 * b2; acc[3][3] += a3 * b3;
        }
        __syncthreads();
    }

    #pragma unroll
    for (int i = 0; i < 4; ++i) {
        int m = m0 + ty * 4 + i;
        #pragma unroll
        for (int j = 0; j < 4; ++j) {
            int n = n0 + tx * 4 + j;
            float v = acc[i][j];
            if (bias) v += bias[n];
            if constexpr (GELU_ACT) v = gelu_exact(v);
            if constexpr (RESID) v += resid[(size_t)m * N + n];
            C[(size_t)m * N + n] = v;
        }
    }
}

// ---------------------------------------------------------------------------
// Causal attention, flash-style. One wave (64 lanes) per (b, h, q-row).
// qkv layout: [B,T,3D]; q at +0, k at +D, v at +2D, head h at h*64.
// Lane d owns output dim d. K tiles of 64 rows staged in padded LDS.
// ---------------------------------------------------------------------------
__global__ __launch_bounds__(64)
void attn_kernel(const float* __restrict__ qkv, float* __restrict__ y)
{
    int bid = blockIdx.x;                 // ((b*H + h)*T + q)
    int q  = bid & (TT - 1);
    int bh = bid >> 11;
    int h  = bh & (HH - 1);
    int b  = bh >> 3;
    int lane = threadIdx.x;

    __shared__ float qs[64];
    __shared__ float ks[64 * 65];

    const size_t rstride = 3 * DD;        // 1536
    const float* base = qkv + (size_t)b * TT * rstride;
    const float scale = 0.125f;           // 1/sqrt(64)

    qs[lane] = base[(size_t)q * rstride + h * HD + lane] * scale;
    __syncthreads();

    float m = -INFINITY, l = 0.0f, acc = 0.0f;

    for (int k0 = 0; k0 <= q; k0 += 64) {
        // stage K tile (rows k0..k0+63, zero-fill masked rows)
        for (int r = 0; r < 64; ++r) {
            int kr = k0 + r;
            float kv = 0.0f;
            if (kr <= q) kv = base[(size_t)kr * rstride + DD + h * HD + lane];
            ks[r * 65 + lane] = kv;
        }
        __syncthreads();

        // lane computes score for k-row (k0+lane)
        float s = 0.0f;
        #pragma unroll
        for (int d = 0; d < 64; ++d)
            s += qs[d] * ks[lane * 65 + d];
        if (k0 + lane > q) s = -INFINITY;

        float tm = s;
        #pragma unroll
        for (int o = 32; o; o >>= 1) tm = fmaxf(tm, __shfl_xor(tm, o));
        float mnew = fmaxf(m, tm);
        float corr = expf(m - mnew);      // m=-inf -> 0
        float p = expf(s - mnew);         // masked -> 0
        l = l * corr + p;                 // per-lane partial sum
        acc *= corr;

        int jmax = min(64, q - k0 + 1);
        for (int j = 0; j < jmax; ++j) {
            float pj = __shfl(p, j);
            acc += pj * base[(size_t)(k0 + j) * rstride + 2 * DD + h * HD + lane];
        }
        m = mnew;
        __syncthreads();
    }

    float lt = l;
    #pragma unroll
    for (int o = 32; o; o >>= 1) lt += __shfl_xor(lt, o);

    y[((size_t)(b * TT + q)) * DD + h * HD + lane] = acc / lt;
}

// ---------------------------------------------------------------------------
// Host-side launch
// ---------------------------------------------------------------------------
extern "C" void kernel_launch(void* const* d_in, const int* in_sizes, int n_in,
                              void* d_out, int out_size, void* d_ws, size_t ws_size,
                              hipStream_t stream)
{
    const int*   idx    = (const int*)  d_in[0];
    const float* wte    = (const float*)d_in[1];
    const float* wpe    = (const float*)d_in[2];
    const float* ln1_g  = (const float*)d_in[3];
    const float* ln1_b  = (const float*)d_in[4];
    const float* qkv_w  = (const float*)d_in[5];
    const float* qkv_b  = (const float*)d_in[6];
    const float* proj_w = (const float*)d_in[7];
    const float* proj_b = (const float*)d_in[8];
    const float* ln2_g  = (const float*)d_in[9];
    const float* ln2_b  = (const float*)d_in[10];
    const float* fc1_w  = (const float*)d_in[11];
    const float* fc1_b  = (const float*)d_in[12];
    const float* fc2_w  = (const float*)d_in[13];
    const float* fc2_b  = (const float*)d_in[14];
    const float* lnf_g  = (const float*)d_in[15];
    const float* lnf_b  = (const float*)d_in[16];
    float* out = (float*)d_out;

    // workspace layout (floats). ff aliases qkv (lifetimes disjoint).
    float* x    = (float*)d_ws;                 // [M, D]
    float* h    = x + (size_t)MM * DD;          // [M, D]
    float* y    = h + (size_t)MM * DD;          // [M, D]
    float* big  = y + (size_t)MM * DD;          // max(M*3D, M*F) = M*F
    float* qkvb = big;                          // [M, 3D]
    float* ffb  = big;                          // [M, F]

    embed_kernel<<<MM, 128, 0, stream>>>(idx, wte, wpe, x);

    for (int l = 0; l < LL; ++l) {
        ln_kernel<<<MM, 256, 0, stream>>>(x, ln1_g + l * DD, ln1_b + l * DD, h);

        gemm_kernel<false, false, false><<<dim3((3 * DD) / 64, MM / 64), 256, 0, stream>>>(
            h, qkv_w + (size_t)l * DD * 3 * DD, qkv_b + (size_t)l * 3 * DD,
            nullptr, qkvb, MM, 3 * DD, DD);

        attn_kernel<<<BB * HH * TT, 64, 0, stream>>>(qkvb, y);

        gemm_kernel<false, false, true><<<dim3(DD / 64, MM / 64), 256, 0, stream>>>(
            y, proj_w + (size_t)l * DD * DD, proj_b + (size_t)l * DD,
            x, x, MM, DD, DD);

        ln_kernel<<<MM, 256, 0, stream>>>(x, ln2_g + l * DD, ln2_b + l * DD, h);

        gemm_kernel<false, true, false><<<dim3(FF / 64, MM / 64), 256, 0, stream>>>(
            h, fc1_w + (size_t)l * DD * FF, fc1_b + (size_t)l * FF,
            nullptr, ffb, MM, FF, DD);

        gemm_kernel<false, false, true><<<dim3(DD / 64, MM / 64), 256, 0, stream>>>(
            ffb, fc2_w + (size_t)l * FF * DD, fc2_b + (size_t)l * DD,
            x, x, MM, DD, FF);
    }

    ln_kernel<<<MM, 256, 0, stream>>>(x, lnf_g, lnf_b, h);

    // logits = h @ wte.T   (wte is [V, D] -> TRANSB)
    gemm_kernel<true, false, false><<<dim3(VV / 64, MM / 64), 256, 0, stream>>>(
        h, wte, nullptr, nullptr, out, MM, VV, DD);
}

// Round 2
// 7179.050 us; speedup vs baseline: 4.3997x; 4.3997x over previous
//
#include <hip/hip_runtime.h>
#include <hip/hip_bf16.h>
#include <math.h>

// Problem constants
#define BB 2
#define TT 2048
#define DD 512
#define HH 8
#define HD 64
#define FF 2048
#define VV 32000
#define LL 6
#define MM (BB * TT)   // 4096

// ---------------------------------------------------------------------------
// Embedding: x[b,t,:] = wte[idx[b,t],:] + wpe[t,:]
// ---------------------------------------------------------------------------
__global__ __launch_bounds__(128)
void embed_kernel(const int* __restrict__ idx, const float* __restrict__ wte,
                  const float* __restrict__ wpe, float* __restrict__ x)
{
    int row = blockIdx.x;            // b*T + t
    int t = row & (TT - 1);
    int tok = idx[row];
    const float4* wt = (const float4*)(wte + (size_t)tok * DD);
    const float4* wp = (const float4*)(wpe + (size_t)t * DD);
    float4 a = wt[threadIdx.x];
    float4 p = wp[threadIdx.x];
    float4 r;
    r.x = a.x + p.x; r.y = a.y + p.y; r.z = a.z + p.z; r.w = a.w + p.w;
    ((float4*)(x + (size_t)row * DD))[threadIdx.x] = r;
}

// ---------------------------------------------------------------------------
// LayerNorm over rows of length 512. 1 block (256 threads) per row.
// ---------------------------------------------------------------------------
__global__ __launch_bounds__(256)
void ln_kernel(const float* __restrict__ x, const float* __restrict__ g,
               const float* __restrict__ b, float* __restrict__ out)
{
    int row = blockIdx.x;
    const float* xr = x + (size_t)row * DD;
    int tid = threadIdx.x;
    float v1 = xr[tid], v2 = xr[tid + 256];
    float s = v1 + v2;
    float ss = v1 * v1 + v2 * v2;
    #pragma unroll
    for (int o = 32; o; o >>= 1) {
        s  += __shfl_xor(s, o);
        ss += __shfl_xor(ss, o);
    }
    __shared__ float sred[4], ssred[4];
    int wid = tid >> 6, lane = tid & 63;
    if (lane == 0) { sred[wid] = s; ssred[wid] = ss; }
    __syncthreads();
    s  = sred[0] + sred[1] + sred[2] + sred[3];
    ss = ssred[0] + ssred[1] + ssred[2] + ssred[3];
    float mu  = s * (1.0f / DD);
    float var = ss * (1.0f / DD) - mu * mu;
    float rs  = rsqrtf(var + 1e-5f);
    float* orow = out + (size_t)row * DD;
    orow[tid]       = (v1 - mu) * rs * g[tid]       + b[tid];
    orow[tid + 256] = (v2 - mu) * rs * g[tid + 256] + b[tid + 256];
}

// ---------------------------------------------------------------------------
// fp32 GEMM: C[M,N] = epilogue(A[M,K] @ B + bias)
// ---------------------------------------------------------------------------
__device__ __forceinline__ float gelu_exact(float v)
{
    return 0.5f * v * (1.0f + erff(v * 0.70710678118654752440f));
}

template<bool TRANSB, bool GELU_ACT, bool RESID>
__global__ __launch_bounds__(256)
void gemm_kernel(const float* __restrict__ A, const float* __restrict__ Bmat,
                 const float* __restrict__ bias, const float* __restrict__ resid,
                 float* __restrict__ C, int M, int N, int K)
{
    __shared__ float As[64][17];
    __shared__ float Bs[16][64];
    __shared__ float BsT[64][17];

    int tid = threadIdx.x;
    int tx = tid & 15, ty = tid >> 4;
    int m0 = blockIdx.y * 64, n0 = blockIdx.x * 64;

    float acc[4][4] = {};

    int ar = tid >> 2, ac = (tid & 3) * 4;
    int br = tid >> 4, bc = (tid & 15) * 4;

    for (int k0 = 0; k0 < K; k0 += 16) {
        float4 av = *(const float4*)(A + (size_t)(m0 + ar) * K + k0 + ac);
        As[ar][ac + 0] = av.x; As[ar][ac + 1] = av.y;
        As[ar][ac + 2] = av.z; As[ar][ac + 3] = av.w;
        if constexpr (!TRANSB) {
            float4 bv = *(const float4*)(Bmat + (size_t)(k0 + br) * N + n0 + bc);
            *(float4*)&Bs[br][bc] = bv;
        } else {
            float4 bv = *(const float4*)(Bmat + (size_t)(n0 + ar) * K + k0 + ac);
            BsT[ar][ac + 0] = bv.x; BsT[ar][ac + 1] = bv.y;
            BsT[ar][ac + 2] = bv.z; BsT[ar][ac + 3] = bv.w;
        }
        __syncthreads();
        #pragma unroll
        for (int kk = 0; kk < 16; ++kk) {
            float a0 = As[ty * 4 + 0][kk];
            float a1 = As[ty * 4 + 1][kk];
            float a2 = As[ty * 4 + 2][kk];
            float a3 = As[ty * 4 + 3][kk];
            float b0, b1, b2, b3;
            if constexpr (!TRANSB) {
                float4 bv = *(const float4*)&Bs[kk][tx * 4];
                b0 = bv.x; b1 = bv.y; b2 = bv.z; b3 = bv.w;
            } else {
                b0 = BsT[tx * 4 + 0][kk];
                b1 = BsT[tx * 4 + 1][kk];
                b2 = BsT[tx * 4 + 2][kk];
                b3 = BsT[tx * 4 + 3][kk];
            }
            acc[0][0] += a0 * b0; acc[0][1] += a0 * b1; acc[0][2] += a0 * b2; acc[0][3] += a0 * b3;
            acc[1][0] += a1 * b0; acc[1][1] += a1 * b1; acc[1][2] += a1 * b2; acc[1][3] += a1 * b3;
            acc[2][0] += a2 * b0; acc[2][1] += a2 * b1; acc[2][2] += a2 * b2; acc[2][3] += a2 * b3;
            acc[3][0] += a3 * b0; acc[3][1] += a3 * b1; acc[3][2] += a3 * b2; acc[3][3] += a3 * b3;
        }
        __syncthreads();
    }

    #pragma unroll
    for (int i = 0; i < 4; ++i) {
        int m = m0 + ty * 4 + i;
        #pragma unroll
        for (int j = 0; j < 4; ++j) {
            int n = n0 + tx * 4 + j;
            float v = acc[i][j];
            if (bias) v += bias[n];
            if constexpr (GELU_ACT) v = gelu_exact(v);
            if constexpr (RESID) v += resid[(size_t)m * N + n];
            C[(size_t)m * N + n] = v;
        }
    }
}

// ---------------------------------------------------------------------------
// Flash attention v2: one block (256 threads, 4 waves) per (b,h,q-tile).
// Q-tile 64 rows staged in LDS (scaled). Per K-tile of 64:
//   stage K,V -> S = Q K^T (4x4 per thread, k = tx + 16*j) -> wave-local
//   16-lane shfl softmax -> P written into K buffer (aliased) -> PV.
// Padded LDS stride 68 floats: 16B-aligned rows, 2-way bank aliasing (free).
// ---------------------------------------------------------------------------
__global__ __launch_bounds__(256)
void attn_kernel(const float* __restrict__ qkv, float* __restrict__ y)
{
    int qt = blockIdx.x;
    int bh = blockIdx.y;
    int h = bh & (HH - 1);
    int b = bh >> 3;

    __shared__ float Qs[64][68];
    __shared__ float KP[64][68];   // K tile, then P tile (disjoint lifetimes)
    __shared__ float Vs[64][68];

    int tid = threadIdx.x;
    int tx = tid & 15, ty = tid >> 4;
    int q0 = qt * 64;

    const size_t rstride = 3 * DD;
    const float* base = qkv + (size_t)b * TT * rstride + h * HD;

    // stage Q (pre-scaled by 1/sqrt(hd))
    {
        int r = tid >> 2, c4 = tid & 3;
        const float* qrow = base + (size_t)(q0 + r) * rstride;
        #pragma unroll
        for (int j = 0; j < 4; ++j) {
            int c = j * 16 + c4 * 4;
            float4 v = *(const float4*)(qrow + c);
            v.x *= 0.125f; v.y *= 0.125f; v.z *= 0.125f; v.w *= 0.125f;
            *(float4*)&Qs[r][c] = v;
        }
    }

    float m[4], l[4], acc[4][4];
    #pragma unroll
    for (int i = 0; i < 4; ++i) {
        m[i] = -INFINITY; l[i] = 0.0f;
        #pragma unroll
        for (int j = 0; j < 4; ++j) acc[i][j] = 0.0f;
    }

    for (int kt = 0; kt <= qt; ++kt) {
        int k0 = kt * 64;
        __syncthreads();                     // prev PV done before restage
        {
            int r = tid >> 2, c4 = tid & 3;
            const float* krow = base + (size_t)(k0 + r) * rstride + DD;
            const float* vrow = krow + DD;
            #pragma unroll
            for (int j = 0; j < 4; ++j) {
                int c = j * 16 + c4 * 4;
                *(float4*)&KP[r][c] = *(const float4*)(krow + c);
                *(float4*)&Vs[r][c] = *(const float4*)(vrow + c);
            }
        }
        __syncthreads();

        // S: s[i][j] = sum_d Q[q0+ty*4+i][d] * K[k0+tx+16j][d]
        float s[4][4] = {};
        #pragma unroll 4
        for (int d4 = 0; d4 < 64; d4 += 4) {
            float4 qv[4], kv[4];
            #pragma unroll
            for (int i = 0; i < 4; ++i) qv[i] = *(const float4*)&Qs[ty * 4 + i][d4];
            #pragma unroll
            for (int j = 0; j < 4; ++j) kv[j] = *(const float4*)&KP[tx + 16 * j][d4];
            #pragma unroll
            for (int i = 0; i < 4; ++i)
                #pragma unroll
                for (int j = 0; j < 4; ++j)
                    s[i][j] += qv[i].x * kv[j].x + qv[i].y * kv[j].y
                             + qv[i].z * kv[j].z + qv[i].w * kv[j].w;
        }

        if (kt == qt) {
            #pragma unroll
            for (int i = 0; i < 4; ++i)
                #pragma unroll
                for (int j = 0; j < 4; ++j)
                    if (tx + 16 * j > ty * 4 + i) s[i][j] = -INFINITY;
        }

        float corr[4];
        #pragma unroll
        for (int i = 0; i < 4; ++i) {
            float tm = fmaxf(fmaxf(s[i][0], s[i][1]), fmaxf(s[i][2], s[i][3]));
            #pragma unroll
            for (int o = 1; o < 16; o <<= 1) tm = fmaxf(tm, __shfl_xor(tm, o));
            float mn = fmaxf(m[i], tm);
            corr[i] = __expf(m[i] - mn);     // m=-inf -> 0
            m[i] = mn;
            float ps = 0.0f;
            #pragma unroll
            for (int j = 0; j < 4; ++j) { s[i][j] = __expf(s[i][j] - mn); ps += s[i][j]; }
            #pragma unroll
            for (int o = 1; o < 16; o <<= 1) ps += __shfl_xor(ps, o);
            l[i] = l[i] * corr[i] + ps;
        }

        __syncthreads();                     // all waves done reading K tile
        #pragma unroll
        for (int i = 0; i < 4; ++i) {
            #pragma unroll
            for (int j = 0; j < 4; ++j) {
                KP[ty * 4 + i][tx + 16 * j] = s[i][j];
                acc[i][j] *= corr[i];
            }
        }
        __syncthreads();                     // P visible

        // PV: acc[i][j] += sum_k P[q][k] * V[k][tx*4+j]
        #pragma unroll 2
        for (int k4 = 0; k4 < 64; k4 += 4) {
            float4 pv[4], vv[4];
            #pragma unroll
            for (int i = 0; i < 4; ++i) pv[i] = *(const float4*)&KP[ty * 4 + i][k4];
            #pragma unroll
            for (int r = 0; r < 4; ++r) vv[r] = *(const float4*)&Vs[k4 + r][tx * 4];
            #pragma unroll
            for (int i = 0; i < 4; ++i) {
                acc[i][0] += pv[i].x * vv[0].x + pv[i].y * vv[1].x + pv[i].z * vv[2].x + pv[i].w * vv[3].x;
                acc[i][1] += pv[i].x * vv[0].y + pv[i].y * vv[1].y + pv[i].z * vv[2].y + pv[i].w * vv[3].y;
                acc[i][2] += pv[i].x * vv[0].z + pv[i].y * vv[1].z + pv[i].z * vv[2].z + pv[i].w * vv[3].z;
                acc[i][3] += pv[i].x * vv[0].w + pv[i].y * vv[1].w + pv[i].z * vv[2].w + pv[i].w * vv[3].w;
            }
        }
    }

    #pragma unroll
    for (int i = 0; i < 4; ++i) {
        int q = q0 + ty * 4 + i;
        float inv = 1.0f / l[i];
        float4 o;
        o.x = acc[i][0] * inv; o.y = acc[i][1] * inv;
        o.z = acc[i][2] * inv; o.w = acc[i][3] * inv;
        *(float4*)(y + (size_t)(b * TT + q) * DD + h * HD + tx * 4) = o;
    }
}

// ---------------------------------------------------------------------------
// Host-side launch
// ---------------------------------------------------------------------------
extern "C" void kernel_launch(void* const* d_in, const int* in_sizes, int n_in,
                              void* d_out, int out_size, void* d_ws, size_t ws_size,
                              hipStream_t stream)
{
    const int*   idx    = (const int*)  d_in[0];
    const float* wte    = (const float*)d_in[1];
    const float* wpe    = (const float*)d_in[2];
    const float* ln1_g  = (const float*)d_in[3];
    const float* ln1_b  = (const float*)d_in[4];
    const float* qkv_w  = (const float*)d_in[5];
    const float* qkv_b  = (const float*)d_in[6];
    const float* proj_w = (const float*)d_in[7];
    const float* proj_b = (const float*)d_in[8];
    const float* ln2_g  = (const float*)d_in[9];
    const float* ln2_b  = (const float*)d_in[10];
    const float* fc1_w  = (const float*)d_in[11];
    const float* fc1_b  = (const float*)d_in[12];
    const float* fc2_w  = (const float*)d_in[13];
    const float* fc2_b  = (const float*)d_in[14];
    const float* lnf_g  = (const float*)d_in[15];
    const float* lnf_b  = (const float*)d_in[16];
    float* out = (float*)d_out;

    float* x    = (float*)d_ws;                 // [M, D]
    float* h    = x + (size_t)MM * DD;          // [M, D]
    float* y    = h + (size_t)MM * DD;          // [M, D]
    float* big  = y + (size_t)MM * DD;          // max(M*3D, M*F) = M*F
    float* qkvb = big;                          // [M, 3D]
    float* ffb  = big;                          // [M, F]

    embed_kernel<<<MM, 128, 0, stream>>>(idx, wte, wpe, x);

    for (int l = 0; l < LL; ++l) {
        ln_kernel<<<MM, 256, 0, stream>>>(x, ln1_g + l * DD, ln1_b + l * DD, h);

        gemm_kernel<false, false, false><<<dim3((3 * DD) / 64, MM / 64), 256, 0, stream>>>(
            h, qkv_w + (size_t)l * DD * 3 * DD, qkv_b + (size_t)l * 3 * DD,
            nullptr, qkvb, MM, 3 * DD, DD);

        attn_kernel<<<dim3(TT / 64, BB * HH), 256, 0, stream>>>(qkvb, y);

        gemm_kernel<false, false, true><<<dim3(DD / 64, MM / 64), 256, 0, stream>>>(
            y, proj_w + (size_t)l * DD * DD, proj_b + (size_t)l * DD,
            x, x, MM, DD, DD);

        ln_kernel<<<MM, 256, 0, stream>>>(x, ln2_g + l * DD, ln2_b + l * DD, h);

        gemm_kernel<false, true, false><<<dim3(FF / 64, MM / 64), 256, 0, stream>>>(
            h, fc1_w + (size_t)l * DD * FF, fc1_b + (size_t)l * FF,
            nullptr, ffb, MM, FF, DD);

        gemm_kernel<false, false, true><<<dim3(DD / 64, MM / 64), 256, 0, stream>>>(
            ffb, fc2_w + (size_t)l * FF * DD, fc2_b + (size_t)l * DD,
            x, x, MM, DD, FF);
    }

    ln_kernel<<<MM, 256, 0, stream>>>(x, lnf_g, lnf_b, h);

    gemm_kernel<true, false, false><<<dim3(VV / 64, MM / 64), 256, 0, stream>>>(
        h, wte, nullptr, nullptr, out, MM, VV, DD);
}

// Round 3
// 2797.260 us; speedup vs baseline: 11.2916x; 2.5665x over previous
//
#include <hip/hip_runtime.h>
#include <hip/hip_bf16.h>
#include <math.h>

// Problem constants
#define BB 2
#define TT 2048
#define DD 512
#define HH 8
#define HD 64
#define FF 2048
#define VV 32000
#define LL 6
#define MM (BB * TT)   // 4096

typedef unsigned int   u32;
typedef unsigned short u16;
typedef __attribute__((ext_vector_type(8))) short short8;   // bf16x8 frag (4 VGPR)
typedef __attribute__((ext_vector_type(4))) float f32x4;    // acc frag

__device__ __forceinline__ u16 f2bf_bits(float f)
{
    __hip_bfloat16 h = __float2bfloat16(f);   // RNE
    u16 u;
    __builtin_memcpy(&u, &h, 2);
    return u;
}

__device__ __forceinline__ void gll16(const u16* g, u16* l)
{
    // async global->LDS, 16B per lane; LDS dest = wave-uniform base + lane*16
    __builtin_amdgcn_global_load_lds(
        (const __attribute__((address_space(1))) u32*)g,
        (__attribute__((address_space(3))) u32*)l,
        16, 0, 0);
}

__device__ __forceinline__ float gelu_exact(float v)
{
    return 0.5f * v * (1.0f + erff(v * 0.70710678118654752440f));
}

// ---------------------------------------------------------------------------
// Embedding: x[b,t,:] = wte[idx[b,t],:] + wpe[t,:]   (fp32 out)
// ---------------------------------------------------------------------------
__global__ __launch_bounds__(128)
void embed_kernel(const int* __restrict__ idx, const float* __restrict__ wte,
                  const float* __restrict__ wpe, float* __restrict__ x)
{
    int row = blockIdx.x;
    int t = row & (TT - 1);
    int tok = idx[row];
    const float4* wt = (const float4*)(wte + (size_t)tok * DD);
    const float4* wp = (const float4*)(wpe + (size_t)t * DD);
    float4 a = wt[threadIdx.x];
    float4 p = wp[threadIdx.x];
    float4 r;
    r.x = a.x + p.x; r.y = a.y + p.y; r.z = a.z + p.z; r.w = a.w + p.w;
    ((float4*)(x + (size_t)row * DD))[threadIdx.x] = r;
}

// ---------------------------------------------------------------------------
// LayerNorm (fp32 in, bf16 out). 1 block (256 threads) per row of 512.
// ---------------------------------------------------------------------------
__global__ __launch_bounds__(256)
void ln_kernel(const float* __restrict__ x, const float* __restrict__ g,
               const float* __restrict__ b, u16* __restrict__ out)
{
    int row = blockIdx.x;
    const float* xr = x + (size_t)row * DD;
    int tid = threadIdx.x;
    float v1 = xr[tid], v2 = xr[tid + 256];
    float s = v1 + v2;
    float ss = v1 * v1 + v2 * v2;
    #pragma unroll
    for (int o = 32; o; o >>= 1) {
        s  += __shfl_xor(s, o);
        ss += __shfl_xor(ss, o);
    }
    __shared__ float sred[4], ssred[4];
    int wid = tid >> 6, lane = tid & 63;
    if (lane == 0) { sred[wid] = s; ssred[wid] = ss; }
    __syncthreads();
    s  = sred[0] + sred[1] + sred[2] + sred[3];
    ss = ssred[0] + ssred[1] + ssred[2] + ssred[3];
    float mu  = s * (1.0f / DD);
    float var = ss * (1.0f / DD) - mu * mu;
    float rs  = rsqrtf(var + 1e-5f);
    u16* orow = out + (size_t)row * DD;
    orow[tid]       = f2bf_bits((v1 - mu) * rs * g[tid]       + b[tid]);
    orow[tid + 256] = f2bf_bits((v2 - mu) * rs * g[tid + 256] + b[tid + 256]);
}

// ---------------------------------------------------------------------------
// fp32 [K,N] -> bf16 [N,K] transpose-convert. 32x32 tiles, 256 threads.
// ---------------------------------------------------------------------------
__global__ __launch_bounds__(256)
void transpose_cvt_kernel(const float* __restrict__ in, u16* __restrict__ out,
                          int K, int N)
{
    __shared__ float tile[32][33];
    int n0 = blockIdx.x * 32, k0 = blockIdx.y * 32;
    int tx = threadIdx.x & 31, ty = threadIdx.x >> 5;   // ty 0..7
    #pragma unroll
    for (int i = 0; i < 4; ++i)
        tile[ty + i * 8][tx] = in[(size_t)(k0 + ty + i * 8) * N + n0 + tx];
    __syncthreads();
    #pragma unroll
    for (int i = 0; i < 4; ++i)
        out[(size_t)(n0 + ty + i * 8) * K + k0 + tx] =
            f2bf_bits(tile[tx][ty + i * 8]);
}

// ---------------------------------------------------------------------------
// fp32 -> bf16 flat convert (4 elems/thread)
// ---------------------------------------------------------------------------
__global__ __launch_bounds__(256)
void cvt_kernel(const float* __restrict__ in, u16* __restrict__ out, int n4)
{
    int i = blockIdx.x * 256 + threadIdx.x;
    if (i >= n4) return;
    float4 v = ((const float4*)in)[i];
    ushort4 o;
    o.x = f2bf_bits(v.x); o.y = f2bf_bits(v.y);
    o.z = f2bf_bits(v.z); o.w = f2bf_bits(v.w);
    ((ushort4*)out)[i] = o;
}

// ---------------------------------------------------------------------------
// bf16 MFMA GEMM (m97 structure): C[M,N] = epi(A[M,K] @ Bt[N,K]^T + bias)
// 128x128 tile, BK=64, 256 threads = 4 waves (2x2, 64x64 each).
// A,Bt bf16 row-major with K contiguous. Linear LDS [128][64], staged via
// global_load_lds width 16. mfma_f32_16x16x32_bf16, frags via ds_read_b128.
// ---------------------------------------------------------------------------
template<bool GELU_ACT, bool RESID, bool OUTBF16>
__global__ __launch_bounds__(256)
void mfma_gemm(const u16* __restrict__ A, const u16* __restrict__ Bt,
               const float* __restrict__ bias, const float* __restrict__ resid,
               void* __restrict__ Cout, int M, int N, int K)
{
    __shared__ u16 As[128 * 64];
    __shared__ u16 Bs[128 * 64];

    const int tid  = threadIdx.x;
    const int lane = tid & 63;
    const int w    = tid >> 6;
    const int wr   = w >> 1, wc = w & 1;

    // bijective XCD swizzle (all grids here have nwg % 8 == 0)
    const int nbx = gridDim.x;
    const int nwg = nbx * gridDim.y;
    int bid = blockIdx.y * nbx + blockIdx.x;
    int swz = (bid & 7) * (nwg >> 3) + (bid >> 3);
    const int m0 = (swz / nbx) * 128;
    const int n0 = (swz % nbx) * 128;

    // staging: thread t covers row t>>3 (+32 per pass), cols (t&7)*8..+8
    const int trow = tid >> 3;
    const int tcol = (tid & 7) * 8;
    const u16* ga = A  + (size_t)(m0 + trow) * K + tcol;
    const u16* gb = Bt + (size_t)(n0 + trow) * K + tcol;
    u16* la = As + tid * 8;
    u16* lb = Bs + tid * 8;

    f32x4 acc[4][4] = {};

    const int fr = lane & 15;          // fragment row (m for A, n for B)
    const int fk = (lane >> 4) * 8;    // k-offset within 32-wide slab

    for (int k0 = 0; k0 < K; k0 += 64) {
        #pragma unroll
        for (int p = 0; p < 4; ++p) {
            gll16(ga + k0 + (size_t)p * 32 * K, la + p * 2048);
            gll16(gb + k0 + (size_t)p * 32 * K, lb + p * 2048);
        }
        asm volatile("s_waitcnt vmcnt(0)" ::: "memory");
        __syncthreads();

        #pragma unroll
        for (int ks = 0; ks < 2; ++ks) {
            short8 af[4], bfr[4];
            #pragma unroll
            for (int f = 0; f < 4; ++f) {
                af[f]  = *(const short8*)&As[(wr * 64 + f * 16 + fr) * 64 + ks * 32 + fk];
                bfr[f] = *(const short8*)&Bs[(wc * 64 + f * 16 + fr) * 64 + ks * 32 + fk];
            }
            #pragma unroll
            for (int i = 0; i < 4; ++i)
                #pragma unroll
                for (int j = 0; j < 4; ++j)
                    acc[i][j] = __builtin_amdgcn_mfma_f32_16x16x32_bf16(
                        af[i], bfr[j], acc[i][j], 0, 0, 0);
        }
        __syncthreads();
    }

    // epilogue: C row = m0+wr*64+i*16+(lane>>4)*4+r, col = n0+wc*64+j*16+(lane&15)
    const int c0 = n0 + wc * 64 + fr;
    const int r0 = m0 + wr * 64 + ((lane >> 4) << 2);
    #pragma unroll
    for (int j = 0; j < 4; ++j) {
        const int c = c0 + j * 16;
        const float bv = bias ? bias[c] : 0.0f;
        #pragma unroll
        for (int i = 0; i < 4; ++i) {
            #pragma unroll
            for (int r = 0; r < 4; ++r) {
                const int row = r0 + i * 16 + r;
                float v = acc[i][j][r] + bv;
                if constexpr (GELU_ACT) v = gelu_exact(v);
                if constexpr (RESID) v += resid[(size_t)row * N + c];
                if constexpr (OUTBF16)
                    ((u16*)Cout)[(size_t)row * N + c] = f2bf_bits(v);
                else
                    ((float*)Cout)[(size_t)row * N + c] = v;
            }
        }
    }
}

// ---------------------------------------------------------------------------
// Flash attention (fp32 compute, bf16 out). One block per (b,h,q-tile of 64).
// ---------------------------------------------------------------------------
__global__ __launch_bounds__(256)
void attn_kernel(const float* __restrict__ qkv, u16* __restrict__ y)
{
    int qt = blockIdx.x;
    int bh = blockIdx.y;
    int h = bh & (HH - 1);
    int b = bh >> 3;

    __shared__ float Qs[64][68];
    __shared__ float KP[64][68];
    __shared__ float Vs[64][68];

    int tid = threadIdx.x;
    int tx = tid & 15, ty = tid >> 4;
    int q0 = qt * 64;

    const size_t rstride = 3 * DD;
    const float* base = qkv + (size_t)b * TT * rstride + h * HD;

    {
        int r = tid >> 2, c4 = tid & 3;
        const float* qrow = base + (size_t)(q0 + r) * rstride;
        #pragma unroll
        for (int j = 0; j < 4; ++j) {
            int c = j * 16 + c4 * 4;
            float4 v = *(const float4*)(qrow + c);
            v.x *= 0.125f; v.y *= 0.125f; v.z *= 0.125f; v.w *= 0.125f;
            *(float4*)&Qs[r][c] = v;
        }
    }

    float m[4], l[4], acc[4][4];
    #pragma unroll
    for (int i = 0; i < 4; ++i) {
        m[i] = -INFINITY; l[i] = 0.0f;
        #pragma unroll
        for (int j = 0; j < 4; ++j) acc[i][j] = 0.0f;
    }

    for (int kt = 0; kt <= qt; ++kt) {
        int k0 = kt * 64;
        __syncthreads();
        {
            int r = tid >> 2, c4 = tid & 3;
            const float* krow = base + (size_t)(k0 + r) * rstride + DD;
            const float* vrow = krow + DD;
            #pragma unroll
            for (int j = 0; j < 4; ++j) {
                int c = j * 16 + c4 * 4;
                *(float4*)&KP[r][c] = *(const float4*)(krow + c);
                *(float4*)&Vs[r][c] = *(const float4*)(vrow + c);
            }
        }
        __syncthreads();

        float s[4][4] = {};
        #pragma unroll 4
        for (int d4 = 0; d4 < 64; d4 += 4) {
            float4 qv[4], kv[4];
            #pragma unroll
            for (int i = 0; i < 4; ++i) qv[i] = *(const float4*)&Qs[ty * 4 + i][d4];
            #pragma unroll
            for (int j = 0; j < 4; ++j) kv[j] = *(const float4*)&KP[tx + 16 * j][d4];
            #pragma unroll
            for (int i = 0; i < 4; ++i)
                #pragma unroll
                for (int j = 0; j < 4; ++j)
                    s[i][j] += qv[i].x * kv[j].x + qv[i].y * kv[j].y
                             + qv[i].z * kv[j].z + qv[i].w * kv[j].w;
        }

        if (kt == qt) {
            #pragma unroll
            for (int i = 0; i < 4; ++i)
                #pragma unroll
                for (int j = 0; j < 4; ++j)
                    if (tx + 16 * j > ty * 4 + i) s[i][j] = -INFINITY;
        }

        float corr[4];
        #pragma unroll
        for (int i = 0; i < 4; ++i) {
            float tm = fmaxf(fmaxf(s[i][0], s[i][1]), fmaxf(s[i][2], s[i][3]));
            #pragma unroll
            for (int o = 1; o < 16; o <<= 1) tm = fmaxf(tm, __shfl_xor(tm, o));
            float mn = fmaxf(m[i], tm);
            corr[i] = __expf(m[i] - mn);
            m[i] = mn;
            float ps = 0.0f;
            #pragma unroll
            for (int j = 0; j < 4; ++j) { s[i][j] = __expf(s[i][j] - mn); ps += s[i][j]; }
            #pragma unroll
            for (int o = 1; o < 16; o <<= 1) ps += __shfl_xor(ps, o);
            l[i] = l[i] * corr[i] + ps;
        }

        __syncthreads();
        #pragma unroll
        for (int i = 0; i < 4; ++i) {
            #pragma unroll
            for (int j = 0; j < 4; ++j) {
                KP[ty * 4 + i][tx + 16 * j] = s[i][j];
                acc[i][j] *= corr[i];
            }
        }
        __syncthreads();

        #pragma unroll 2
        for (int k4 = 0; k4 < 64; k4 += 4) {
            float4 pv[4], vv[4];
            #pragma unroll
            for (int i = 0; i < 4; ++i) pv[i] = *(const float4*)&KP[ty * 4 + i][k4];
            #pragma unroll
            for (int r = 0; r < 4; ++r) vv[r] = *(const float4*)&Vs[k4 + r][tx * 4];
            #pragma unroll
            for (int i = 0; i < 4; ++i) {
                acc[i][0] += pv[i].x * vv[0].x + pv[i].y * vv[1].x + pv[i].z * vv[2].x + pv[i].w * vv[3].x;
                acc[i][1] += pv[i].x * vv[0].y + pv[i].y * vv[1].y + pv[i].z * vv[2].y + pv[i].w * vv[3].y;
                acc[i][2] += pv[i].x * vv[0].z + pv[i].y * vv[1].z + pv[i].z * vv[2].z + pv[i].w * vv[3].z;
                acc[i][3] += pv[i].x * vv[0].w + pv[i].y * vv[1].w + pv[i].z * vv[2].w + pv[i].w * vv[3].w;
            }
        }
    }

    #pragma unroll
    for (int i = 0; i < 4; ++i) {
        int q = q0 + ty * 4 + i;
        float inv = 1.0f / l[i];
        ushort4 o;
        o.x = f2bf_bits(acc[i][0] * inv);
        o.y = f2bf_bits(acc[i][1] * inv);
        o.z = f2bf_bits(acc[i][2] * inv);
        o.w = f2bf_bits(acc[i][3] * inv);
        *(ushort4*)(y + (size_t)(b * TT + q) * DD + h * HD + tx * 4) = o;
    }
}

// ---------------------------------------------------------------------------
// Host-side launch
// ---------------------------------------------------------------------------
extern "C" void kernel_launch(void* const* d_in, const int* in_sizes, int n_in,
                              void* d_out, int out_size, void* d_ws, size_t ws_size,
                              hipStream_t stream)
{
    const int*   idx    = (const int*)  d_in[0];
    const float* wte    = (const float*)d_in[1];
    const float* wpe    = (const float*)d_in[2];
    const float* ln1_g  = (const float*)d_in[3];
    const float* ln1_b  = (const float*)d_in[4];
    const float* qkv_w  = (const float*)d_in[5];
    const float* qkv_b  = (const float*)d_in[6];
    const float* proj_w = (const float*)d_in[7];
    const float* proj_b = (const float*)d_in[8];
    const float* ln2_g  = (const float*)d_in[9];
    const float* ln2_b  = (const float*)d_in[10];
    const float* fc1_w  = (const float*)d_in[11];
    const float* fc1_b  = (const float*)d_in[12];
    const float* fc2_w  = (const float*)d_in[13];
    const float* fc2_b  = (const float*)d_in[14];
    const float* lnf_g  = (const float*)d_in[15];
    const float* lnf_b  = (const float*)d_in[16];
    float* out = (float*)d_out;

    // workspace (bytes):
    //   x    fp32 [M,D]            @ 0          (8 MB)
    //   h    bf16 [M,D]            @ 8 MB       (4 MB)
    //   y    bf16 [M,D]            @ 12 MB      (4 MB)
    //   wbuf bf16 per-layer Bt     @ 16 MB      (6.3 MB)
    //   big: qkvb fp32 [M,3D] / ffb bf16 [M,F] / wteb bf16 [V,D]  @ 24 MB (33 MB)
    char* ws = (char*)d_ws;
    float* x    = (float*)(ws);
    u16*   h    = (u16*)(ws + (8u  << 20));
    u16*   y    = (u16*)(ws + (12u << 20));
    u16*   wbuf = (u16*)(ws + (16u << 20));
    char*  big  = ws + (24u << 20);
    float* qkvb = (float*)big;
    u16*   ffb  = (u16*)big;
    u16*   wteb = (u16*)big;

    u16* wq = wbuf;                    // [3D, D] = [1536, 512]
    u16* wp = wq + 1536 * 512;         // [D, D]
    u16* w1 = wp + 512 * 512;          // [F, D]
    u16* w2 = w1 + 2048 * 512;         // [D, F]

    embed_kernel<<<MM, 128, 0, stream>>>(idx, wte, wpe, x);

    for (int l = 0; l < LL; ++l) {
        ln_kernel<<<MM, 256, 0, stream>>>(x, ln1_g + l * DD, ln1_b + l * DD, h);

        transpose_cvt_kernel<<<dim3(48, 16), 256, 0, stream>>>(
            qkv_w + (size_t)l * DD * 3 * DD, wq, DD, 3 * DD);
        mfma_gemm<false, false, false><<<dim3(12, 32), 256, 0, stream>>>(
            h, wq, qkv_b + (size_t)l * 3 * DD, nullptr, qkvb, MM, 3 * DD, DD);

        attn_kernel<<<dim3(TT / 64, BB * HH), 256, 0, stream>>>(qkvb, y);

        transpose_cvt_kernel<<<dim3(16, 16), 256, 0, stream>>>(
            proj_w + (size_t)l * DD * DD, wp, DD, DD);
        mfma_gemm<false, true, false><<<dim3(4, 32), 256, 0, stream>>>(
            y, wp, proj_b + (size_t)l * DD, x, x, MM, DD, DD);

        ln_kernel<<<MM, 256, 0, stream>>>(x, ln2_g + l * DD, ln2_b + l * DD, h);

        transpose_cvt_kernel<<<dim3(64, 16), 256, 0, stream>>>(
            fc1_w + (size_t)l * DD * FF, w1, DD, FF);
        mfma_gemm<true, false, true><<<dim3(16, 32), 256, 0, stream>>>(
            h, w1, fc1_b + (size_t)l * FF, nullptr, ffb, MM, FF, DD);

        transpose_cvt_kernel<<<dim3(16, 64), 256, 0, stream>>>(
            fc2_w + (size_t)l * FF * DD, w2, FF, DD);
        mfma_gemm<false, true, false><<<dim3(4, 32), 256, 0, stream>>>(
            ffb, w2, fc2_b + (size_t)l * DD, x, x, MM, DD, FF);
    }

    ln_kernel<<<MM, 256, 0, stream>>>(x, lnf_g, lnf_b, h);

    cvt_kernel<<<(VV * DD / 4 + 255) / 256, 256, 0, stream>>>(wte, wteb, VV * DD / 4);

    mfma_gemm<false, false, false><<<dim3(250, 32), 256, 0, stream>>>(
        h, wteb, nullptr, nullptr, out, MM, VV, DD);
}

// Round 4
// 1402.866 us; speedup vs baseline: 22.5150x; 1.9940x over previous
//
#include <hip/hip_runtime.h>
#include <hip/hip_bf16.h>
#include <math.h>

// Problem constants
#define BB 2
#define TT 2048
#define DD 512
#define HH 8
#define HD 64
#define FF 2048
#define VV 32000
#define LL 6
#define MM (BB * TT)   // 4096

typedef unsigned int   u32;
typedef unsigned short u16;
typedef __attribute__((ext_vector_type(8))) short short8;   // bf16x8 frag (4 VGPR)
typedef __attribute__((ext_vector_type(4))) float f32x4;    // acc frag

__device__ __forceinline__ u16 f2bf_bits(float f)
{
    __hip_bfloat16 h = __float2bfloat16(f);   // RNE
    u16 u;
    __builtin_memcpy(&u, &h, 2);
    return u;
}

__device__ __forceinline__ void gll16(const u16* g, u16* l)
{
    __builtin_amdgcn_global_load_lds(
        (const __attribute__((address_space(1))) u32*)g,
        (__attribute__((address_space(3))) u32*)l,
        16, 0, 0);
}

__device__ __forceinline__ float gelu_exact(float v)
{
    return 0.5f * v * (1.0f + erff(v * 0.70710678118654752440f));
}

// XOR-swizzled pointer into a [64][64]-u16 LDS tile (row = 128 B).
// Spreads the 16B chunk index by row&7 -> fragment column reads are ~2-way.
__device__ __forceinline__ u16* swp(u16* base, int row, int col)
{
    int off = (row * 128 + col * 2) ^ ((row & 7) << 4);
    return (u16*)((char*)base + off);
}
__device__ __forceinline__ const u16* swpc(const u16* base, int row, int col)
{
    int off = (row * 128 + col * 2) ^ ((row & 7) << 4);
    return (const u16*)((const char*)base + off);
}

// ---------------------------------------------------------------------------
// Embedding: x[b,t,:] = wte[idx[b,t],:] + wpe[t,:]   (fp32 out)
// ---------------------------------------------------------------------------
__global__ __launch_bounds__(128)
void embed_kernel(const int* __restrict__ idx, const float* __restrict__ wte,
                  const float* __restrict__ wpe, float* __restrict__ x)
{
    int row = blockIdx.x;
    int t = row & (TT - 1);
    int tok = idx[row];
    const float4* wt = (const float4*)(wte + (size_t)tok * DD);
    const float4* wp = (const float4*)(wpe + (size_t)t * DD);
    float4 a = wt[threadIdx.x];
    float4 p = wp[threadIdx.x];
    float4 r;
    r.x = a.x + p.x; r.y = a.y + p.y; r.z = a.z + p.z; r.w = a.w + p.w;
    ((float4*)(x + (size_t)row * DD))[threadIdx.x] = r;
}

// ---------------------------------------------------------------------------
// LayerNorm (fp32 in, bf16 out). 1 block (256 threads) per row of 512.
// ---------------------------------------------------------------------------
__global__ __launch_bounds__(256)
void ln_kernel(const float* __restrict__ x, const float* __restrict__ g,
               const float* __restrict__ b, u16* __restrict__ out)
{
    int row = blockIdx.x;
    const float* xr = x + (size_t)row * DD;
    int tid = threadIdx.x;
    float v1 = xr[tid], v2 = xr[tid + 256];
    float s = v1 + v2;
    float ss = v1 * v1 + v2 * v2;
    #pragma unroll
    for (int o = 32; o; o >>= 1) {
        s  += __shfl_xor(s, o);
        ss += __shfl_xor(ss, o);
    }
    __shared__ float sred[4], ssred[4];
    int wid = tid >> 6, lane = tid & 63;
    if (lane == 0) { sred[wid] = s; ssred[wid] = ss; }
    __syncthreads();
    s  = sred[0] + sred[1] + sred[2] + sred[3];
    ss = ssred[0] + ssred[1] + ssred[2] + ssred[3];
    float mu  = s * (1.0f / DD);
    float var = ss * (1.0f / DD) - mu * mu;
    float rs  = rsqrtf(var + 1e-5f);
    u16* orow = out + (size_t)row * DD;
    orow[tid]       = f2bf_bits((v1 - mu) * rs * g[tid]       + b[tid]);
    orow[tid + 256] = f2bf_bits((v2 - mu) * rs * g[tid + 256] + b[tid + 256]);
}

// ---------------------------------------------------------------------------
// fp32 [K,N] -> bf16 [N,K] transpose-convert. 32x32 tiles, 256 threads.
// ---------------------------------------------------------------------------
__global__ __launch_bounds__(256)
void transpose_cvt_kernel(const float* __restrict__ in, u16* __restrict__ out,
                          int K, int N)
{
    __shared__ float tile[32][33];
    int n0 = blockIdx.x * 32, k0 = blockIdx.y * 32;
    int tx = threadIdx.x & 31, ty = threadIdx.x >> 5;
    #pragma unroll
    for (int i = 0; i < 4; ++i)
        tile[ty + i * 8][tx] = in[(size_t)(k0 + ty + i * 8) * N + n0 + tx];
    __syncthreads();
    #pragma unroll
    for (int i = 0; i < 4; ++i)
        out[(size_t)(n0 + ty + i * 8) * K + k0 + tx] =
            f2bf_bits(tile[tx][ty + i * 8]);
}

// ---------------------------------------------------------------------------
// fp32 -> bf16 flat convert (4 elems/thread)
// ---------------------------------------------------------------------------
__global__ __launch_bounds__(256)
void cvt_kernel(const float* __restrict__ in, u16* __restrict__ out, int n4)
{
    int i = blockIdx.x * 256 + threadIdx.x;
    if (i >= n4) return;
    float4 v = ((const float4*)in)[i];
    ushort4 o;
    o.x = f2bf_bits(v.x); o.y = f2bf_bits(v.y);
    o.z = f2bf_bits(v.z); o.w = f2bf_bits(v.w);
    ((ushort4*)out)[i] = o;
}

// ---------------------------------------------------------------------------
// bf16 MFMA GEMM (m97 structure): C[M,N] = epi(A[M,K] @ Bt[N,K]^T + bias)
// ---------------------------------------------------------------------------
template<bool GELU_ACT, bool RESID, bool OUTBF16>
__global__ __launch_bounds__(256)
void mfma_gemm(const u16* __restrict__ A, const u16* __restrict__ Bt,
               const float* __restrict__ bias, const float* __restrict__ resid,
               void* __restrict__ Cout, int M, int N, int K)
{
    __shared__ u16 As[128 * 64];
    __shared__ u16 Bs[128 * 64];

    const int tid  = threadIdx.x;
    const int lane = tid & 63;
    const int w    = tid >> 6;
    const int wr   = w >> 1, wc = w & 1;

    const int nbx = gridDim.x;
    const int nwg = nbx * gridDim.y;
    int bid = blockIdx.y * nbx + blockIdx.x;
    int swz = (bid & 7) * (nwg >> 3) + (bid >> 3);
    const int m0 = (swz / nbx) * 128;
    const int n0 = (swz % nbx) * 128;

    const int trow = tid >> 3;
    const int tcol = (tid & 7) * 8;
    const u16* ga = A  + (size_t)(m0 + trow) * K + tcol;
    const u16* gb = Bt + (size_t)(n0 + trow) * K + tcol;
    u16* la = As + tid * 8;
    u16* lb = Bs + tid * 8;

    f32x4 acc[4][4] = {};

    const int fr = lane & 15;
    const int fk = (lane >> 4) * 8;

    for (int k0 = 0; k0 < K; k0 += 64) {
        #pragma unroll
        for (int p = 0; p < 4; ++p) {
            gll16(ga + k0 + (size_t)p * 32 * K, la + p * 2048);
            gll16(gb + k0 + (size_t)p * 32 * K, lb + p * 2048);
        }
        asm volatile("s_waitcnt vmcnt(0)" ::: "memory");
        __syncthreads();

        #pragma unroll
        for (int ks = 0; ks < 2; ++ks) {
            short8 af[4], bfr[4];
            #pragma unroll
            for (int f = 0; f < 4; ++f) {
                af[f]  = *(const short8*)&As[(wr * 64 + f * 16 + fr) * 64 + ks * 32 + fk];
                bfr[f] = *(const short8*)&Bs[(wc * 64 + f * 16 + fr) * 64 + ks * 32 + fk];
            }
            #pragma unroll
            for (int i = 0; i < 4; ++i)
                #pragma unroll
                for (int j = 0; j < 4; ++j)
                    acc[i][j] = __builtin_amdgcn_mfma_f32_16x16x32_bf16(
                        af[i], bfr[j], acc[i][j], 0, 0, 0);
        }
        __syncthreads();
    }

    const int c0 = n0 + wc * 64 + fr;
    const int r0 = m0 + wr * 64 + ((lane >> 4) << 2);
    #pragma unroll
    for (int j = 0; j < 4; ++j) {
        const int c = c0 + j * 16;
        const float bv = bias ? bias[c] : 0.0f;
        #pragma unroll
        for (int i = 0; i < 4; ++i) {
            #pragma unroll
            for (int r = 0; r < 4; ++r) {
                const int row = r0 + i * 16 + r;
                float v = acc[i][j][r] + bv;
                if constexpr (GELU_ACT) v = gelu_exact(v);
                if constexpr (RESID) v += resid[(size_t)row * N + c];
                if constexpr (OUTBF16)
                    ((u16*)Cout)[(size_t)row * N + c] = f2bf_bits(v);
                else
                    ((float*)Cout)[(size_t)row * N + c] = v;
            }
        }
    }
}

// ---------------------------------------------------------------------------
// bf16 MFMA flash attention. 512 flat blocks, 256 threads (4 waves).
// Block -> (qt, bh) via a CU-pairing remap: co-resident blocks (l, l+256)
// get complementary qt so per-CU causal work is uniform (33 k-tiles).
// Per block: Q-tile 64 rows (wave w owns rows w*16..+16), K-tiles of 64.
// QK^T and PV via mfma_f32_16x16x32_bf16. V staged transposed [d][kv];
// P staged in LDS (A-operand layout). All LDS tiles XOR-swizzled.
// qkv is bf16 [M, 3D]; scale 1/8 folded into S.
// ---------------------------------------------------------------------------
__global__ __launch_bounds__(256)
void attn_kernel(const u16* __restrict__ qkv, u16* __restrict__ y)
{
    const int l = blockIdx.x;
    const int u = l & 255, v = l >> 8;
    const int bh = u & 15;
    const int half = u >> 4;
    const int qt = v ? (16 + half) : (15 - half);
    const int h = bh & (HH - 1);
    const int b = bh >> 3;

    __shared__ alignas(16) u16 Qs[64 * 64];
    __shared__ alignas(16) u16 Ks[64 * 64];
    __shared__ alignas(16) u16 Vt[64 * 64];   // transposed: [d][kv]
    __shared__ alignas(16) u16 Ps[64 * 64];

    const int tid = threadIdx.x;
    const int lane = tid & 63;
    const int w = tid >> 6;
    const int ln = lane & 15, hi = lane >> 4;
    const int q0 = qt * 64;

    const size_t rstride = 3 * DD;            // u16 elems per token row
    const u16* base = qkv + (size_t)b * TT * rstride + h * HD;

    // ---- stage Q (bf16, swizzled) ----
    {
        int r = tid >> 2, c0 = (tid & 3) * 16;
        const u16* qrow = base + (size_t)(q0 + r) * rstride;
        *(short8*)swp(Qs, r, c0)     = *(const short8*)(qrow + c0);
        *(short8*)swp(Qs, r, c0 + 8) = *(const short8*)(qrow + c0 + 8);
    }

    float m[4], lsum[4];
    f32x4 oacc[4] = {};
    #pragma unroll
    for (int r = 0; r < 4; ++r) { m[r] = -INFINITY; lsum[r] = 0.0f; }

    for (int kt = 0; kt <= qt; ++kt) {
        const int k0 = kt * 64;
        __syncthreads();                      // prev tile fully consumed (also Q staged)
        {
            int r = tid >> 2, c0 = (tid & 3) * 16;
            const u16* krow = base + (size_t)(k0 + r) * rstride + DD;
            const u16* vrow = krow + DD;
            *(short8*)swp(Ks, r, c0)     = *(const short8*)(krow + c0);
            *(short8*)swp(Ks, r, c0 + 8) = *(const short8*)(krow + c0 + 8);
            short8 va = *(const short8*)(vrow + c0);
            short8 vb = *(const short8*)(vrow + c0 + 8);
            #pragma unroll
            for (int i = 0; i < 8; ++i) *swp(Vt, c0 + i, r)     = (u16)va[i];
            #pragma unroll
            for (int i = 0; i < 8; ++i) *swp(Vt, c0 + 8 + i, r) = (u16)vb[i];
        }
        __syncthreads();

        // ---- S = Q K^T (wave w: 16 q-rows x 64 k-cols) ----
        short8 aq[2];
        #pragma unroll
        for (int ks = 0; ks < 2; ++ks)
            aq[ks] = *(const short8*)swpc(Qs, w * 16 + ln, ks * 32 + hi * 8);

        f32x4 sacc[4] = {};
        #pragma unroll
        for (int j = 0; j < 4; ++j)
            #pragma unroll
            for (int ks = 0; ks < 2; ++ks) {
                short8 bk = *(const short8*)swpc(Ks, j * 16 + ln, ks * 32 + hi * 8);
                sacc[j] = __builtin_amdgcn_mfma_f32_16x16x32_bf16(aq[ks], bk, sacc[j], 0, 0, 0);
            }

        // ---- online softmax (fp32, scale folded in) ----
        const bool diag = (kt == qt);
        #pragma unroll
        for (int r = 0; r < 4; ++r) {
            const int qrow = w * 16 + hi * 4 + r;
            float sv[4];
            #pragma unroll
            for (int j = 0; j < 4; ++j) {
                float s = sacc[j][r] * 0.125f;
                if (diag && (j * 16 + ln > qrow)) s = -INFINITY;
                sv[j] = s;
            }
            float rm = fmaxf(fmaxf(sv[0], sv[1]), fmaxf(sv[2], sv[3]));
            #pragma unroll
            for (int o = 1; o < 16; o <<= 1) rm = fmaxf(rm, __shfl_xor(rm, o));
            float mn = fmaxf(m[r], rm);
            float corr = __expf(m[r] - mn);
            m[r] = mn;
            float ps = 0.0f;
            #pragma unroll
            for (int j = 0; j < 4; ++j) {
                float p = __expf(sv[j] - mn);
                ps += p;
                *swp(Ps, qrow, j * 16 + ln) = f2bf_bits(p);
            }
            #pragma unroll
            for (int o = 1; o < 16; o <<= 1) ps += __shfl_xor(ps, o);
            lsum[r] = lsum[r] * corr + ps;
            #pragma unroll
            for (int db = 0; db < 4; ++db) oacc[db][r] *= corr;
        }

        // ---- O += P V (reads wave-private Ps rows; Vt staged pre-barrier) ----
        short8 ap[2];
        #pragma unroll
        for (int ks = 0; ks < 2; ++ks)
            ap[ks] = *(const short8*)swpc(Ps, w * 16 + ln, ks * 32 + hi * 8);
        #pragma unroll
        for (int db = 0; db < 4; ++db)
            #pragma unroll
            for (int ks = 0; ks < 2; ++ks) {
                short8 bv = *(const short8*)swpc(Vt, db * 16 + ln, ks * 32 + hi * 8);
                oacc[db] = __builtin_amdgcn_mfma_f32_16x16x32_bf16(ap[ks], bv, oacc[db], 0, 0, 0);
            }
    }

    // ---- epilogue ----
    #pragma unroll
    for (int r = 0; r < 4; ++r) {
        const int q = q0 + w * 16 + hi * 4 + r;
        const float inv = 1.0f / lsum[r];
        u16* yrow = y + (size_t)(b * TT + q) * DD + h * HD;
        #pragma unroll
        for (int db = 0; db < 4; ++db)
            yrow[db * 16 + ln] = f2bf_bits(oacc[db][r] * inv);
    }
}

// ---------------------------------------------------------------------------
// Host-side launch
// ---------------------------------------------------------------------------
extern "C" void kernel_launch(void* const* d_in, const int* in_sizes, int n_in,
                              void* d_out, int out_size, void* d_ws, size_t ws_size,
                              hipStream_t stream)
{
    const int*   idx    = (const int*)  d_in[0];
    const float* wte    = (const float*)d_in[1];
    const float* wpe    = (const float*)d_in[2];
    const float* ln1_g  = (const float*)d_in[3];
    const float* ln1_b  = (const float*)d_in[4];
    const float* qkv_w  = (const float*)d_in[5];
    const float* qkv_b  = (const float*)d_in[6];
    const float* proj_w = (const float*)d_in[7];
    const float* proj_b = (const float*)d_in[8];
    const float* ln2_g  = (const float*)d_in[9];
    const float* ln2_b  = (const float*)d_in[10];
    const float* fc1_w  = (const float*)d_in[11];
    const float* fc1_b  = (const float*)d_in[12];
    const float* fc2_w  = (const float*)d_in[13];
    const float* fc2_b  = (const float*)d_in[14];
    const float* lnf_g  = (const float*)d_in[15];
    const float* lnf_b  = (const float*)d_in[16];
    float* out = (float*)d_out;

    // workspace:
    //   x    fp32 [M,D]        @ 0     (8 MB)
    //   h    bf16 [M,D]        @ 8 MB  (4 MB)
    //   y    bf16 [M,D]        @ 12 MB (4 MB)
    //   wbuf bf16 weights      @ 16 MB (6.3 MB)
    //   big: qkvb bf16 [M,3D] (12.6MB) / ffb bf16 [M,F] (16.8MB) / wteb (32.8MB)
    char* ws = (char*)d_ws;
    float* x    = (float*)(ws);
    u16*   h    = (u16*)(ws + (8u  << 20));
    u16*   y    = (u16*)(ws + (12u << 20));
    u16*   wbuf = (u16*)(ws + (16u << 20));
    char*  big  = ws + (24u << 20);
    u16*   qkvb = (u16*)big;
    u16*   ffb  = (u16*)big;
    u16*   wteb = (u16*)big;

    u16* wq = wbuf;                    // [3D, D]
    u16* wp = wq + 1536 * 512;         // [D, D]
    u16* w1 = wp + 512 * 512;          // [F, D]
    u16* w2 = w1 + 2048 * 512;         // [D, F]

    embed_kernel<<<MM, 128, 0, stream>>>(idx, wte, wpe, x);

    for (int l = 0; l < LL; ++l) {
        ln_kernel<<<MM, 256, 0, stream>>>(x, ln1_g + l * DD, ln1_b + l * DD, h);

        transpose_cvt_kernel<<<dim3(48, 16), 256, 0, stream>>>(
            qkv_w + (size_t)l * DD * 3 * DD, wq, DD, 3 * DD);
        mfma_gemm<false, false, true><<<dim3(12, 32), 256, 0, stream>>>(
            h, wq, qkv_b + (size_t)l * 3 * DD, nullptr, qkvb, MM, 3 * DD, DD);

        attn_kernel<<<512, 256, 0, stream>>>(qkvb, y);

        transpose_cvt_kernel<<<dim3(16, 16), 256, 0, stream>>>(
            proj_w + (size_t)l * DD * DD, wp, DD, DD);
        mfma_gemm<false, true, false><<<dim3(4, 32), 256, 0, stream>>>(
            y, wp, proj_b + (size_t)l * DD, x, x, MM, DD, DD);

        ln_kernel<<<MM, 256, 0, stream>>>(x, ln2_g + l * DD, ln2_b + l * DD, h);

        transpose_cvt_kernel<<<dim3(64, 16), 256, 0, stream>>>(
            fc1_w + (size_t)l * DD * FF, w1, DD, FF);
        mfma_gemm<true, false, true><<<dim3(16, 32), 256, 0, stream>>>(
            h, w1, fc1_b + (size_t)l * FF, nullptr, ffb, MM, FF, DD);

        transpose_cvt_kernel<<<dim3(16, 64), 256, 0, stream>>>(
            fc2_w + (size_t)l * FF * DD, w2, FF, DD);
        mfma_gemm<false, true, false><<<dim3(4, 32), 256, 0, stream>>>(
            ffb, w2, fc2_b + (size_t)l * DD, x, x, MM, DD, FF);
    }

    ln_kernel<<<MM, 256, 0, stream>>>(x, lnf_g, lnf_b, h);

    cvt_kernel<<<(VV * DD / 4 + 255) / 256, 256, 0, stream>>>(wte, wteb, VV * DD / 4);

    mfma_gemm<false, false, false><<<dim3(250, 32), 256, 0, stream>>>(
        h, wteb, nullptr, nullptr, out, MM, VV, DD);
}

// Round 5
// 1247.933 us; speedup vs baseline: 25.3102x; 1.1242x over previous
//
#include <hip/hip_runtime.h>
#include <hip/hip_bf16.h>
#include <math.h>

// Problem constants
#define BB 2
#define TT 2048
#define DD 512
#define HH 8
#define HD 64
#define FF 2048
#define VV 32000
#define LL 6
#define MM (BB * TT)   // 4096

typedef unsigned int   u32;
typedef unsigned short u16;
typedef __attribute__((ext_vector_type(8))) short short8;   // bf16x8 frag (4 VGPR)
typedef __attribute__((ext_vector_type(4))) float f32x4;    // acc frag

__device__ __forceinline__ u16 f2bf_bits(float f)
{
    __hip_bfloat16 h = __float2bfloat16(f);   // RNE
    u16 u;
    __builtin_memcpy(&u, &h, 2);
    return u;
}

__device__ __forceinline__ void gll16(const u16* g, u16* l)
{
    __builtin_amdgcn_global_load_lds(
        (const __attribute__((address_space(1))) u32*)g,
        (__attribute__((address_space(3))) u32*)l,
        16, 0, 0);
}

__device__ __forceinline__ float gelu_exact(float v)
{
    return 0.5f * v * (1.0f + erff(v * 0.70710678118654752440f));
}

// XOR-swizzled pointer into a [64][64]-u16 LDS tile (row = 128 B).
__device__ __forceinline__ u16* swp(u16* base, int row, int col)
{
    int off = (row * 128 + col * 2) ^ ((row & 7) << 4);
    return (u16*)((char*)base + off);
}
__device__ __forceinline__ const u16* swpc(const u16* base, int row, int col)
{
    int off = (row * 128 + col * 2) ^ ((row & 7) << 4);
    return (const u16*)((const char*)base + off);
}

// ---------------------------------------------------------------------------
// Embedding: x[b,t,:] = wte[idx[b,t],:] + wpe[t,:]   (fp32 out)
// ---------------------------------------------------------------------------
__global__ __launch_bounds__(128)
void embed_kernel(const int* __restrict__ idx, const float* __restrict__ wte,
                  const float* __restrict__ wpe, float* __restrict__ x)
{
    int row = blockIdx.x;
    int t = row & (TT - 1);
    int tok = idx[row];
    const float4* wt = (const float4*)(wte + (size_t)tok * DD);
    const float4* wp = (const float4*)(wpe + (size_t)t * DD);
    float4 a = wt[threadIdx.x];
    float4 p = wp[threadIdx.x];
    float4 r;
    r.x = a.x + p.x; r.y = a.y + p.y; r.z = a.z + p.z; r.w = a.w + p.w;
    ((float4*)(x + (size_t)row * DD))[threadIdx.x] = r;
}

// ---------------------------------------------------------------------------
// LayerNorm (fp32 in, bf16 out). 1 block (256 threads) per row of 512.
// ---------------------------------------------------------------------------
__global__ __launch_bounds__(256)
void ln_kernel(const float* __restrict__ x, const float* __restrict__ g,
               const float* __restrict__ b, u16* __restrict__ out)
{
    int row = blockIdx.x;
    const float* xr = x + (size_t)row * DD;
    int tid = threadIdx.x;
    float v1 = xr[tid], v2 = xr[tid + 256];
    float s = v1 + v2;
    float ss = v1 * v1 + v2 * v2;
    #pragma unroll
    for (int o = 32; o; o >>= 1) {
        s  += __shfl_xor(s, o);
        ss += __shfl_xor(ss, o);
    }
    __shared__ float sred[4], ssred[4];
    int wid = tid >> 6, lane = tid & 63;
    if (lane == 0) { sred[wid] = s; ssred[wid] = ss; }
    __syncthreads();
    s  = sred[0] + sred[1] + sred[2] + sred[3];
    ss = ssred[0] + ssred[1] + ssred[2] + ssred[3];
    float mu  = s * (1.0f / DD);
    float var = ss * (1.0f / DD) - mu * mu;
    float rs  = rsqrtf(var + 1e-5f);
    u16* orow = out + (size_t)row * DD;
    orow[tid]       = f2bf_bits((v1 - mu) * rs * g[tid]       + b[tid]);
    orow[tid + 256] = f2bf_bits((v2 - mu) * rs * g[tid + 256] + b[tid + 256]);
}

// ---------------------------------------------------------------------------
// Weight prep: ALL layers' fp32 [K,N] -> bf16 [N,K] transposes in one launch.
// Per-layer tiles (32x32): qkv 768, proj 256, fc1 1024, fc2 1024 = 3072.
// grid = 6 * 3072 = 18432 blocks, 256 threads.
// ---------------------------------------------------------------------------
__global__ __launch_bounds__(256)
void weight_prep_kernel(const float* __restrict__ qkv_w, const float* __restrict__ proj_w,
                        const float* __restrict__ fc1_w, const float* __restrict__ fc2_w,
                        u16* __restrict__ wqa, u16* __restrict__ wpa,
                        u16* __restrict__ w1a, u16* __restrict__ w2a)
{
    int id = blockIdx.x;
    int l = id / 3072, r = id % 3072;
    const float* in; u16* out; int K, N, tt;
    if (r < 768)       { in = qkv_w + (size_t)l * DD * 3 * DD; out = wqa + (size_t)l * 3 * DD * DD; K = DD; N = 3 * DD; tt = r; }
    else if (r < 1024) { in = proj_w + (size_t)l * DD * DD;    out = wpa + (size_t)l * DD * DD;    K = DD; N = DD;     tt = r - 768; }
    else if (r < 2048) { in = fc1_w + (size_t)l * DD * FF;     out = w1a + (size_t)l * DD * FF;    K = DD; N = FF;     tt = r - 1024; }
    else               { in = fc2_w + (size_t)l * FF * DD;     out = w2a + (size_t)l * FF * DD;    K = FF; N = DD;     tt = r - 2048; }
    int ntx = N >> 5;
    int n0 = (tt % ntx) << 5, k0 = (tt / ntx) << 5;
    __shared__ float tile[32][33];
    int tx = threadIdx.x & 31, ty = threadIdx.x >> 5;
    #pragma unroll
    for (int i = 0; i < 4; ++i)
        tile[ty + i * 8][tx] = in[(size_t)(k0 + ty + i * 8) * N + n0 + tx];
    __syncthreads();
    #pragma unroll
    for (int i = 0; i < 4; ++i)
        out[(size_t)(n0 + ty + i * 8) * K + k0 + tx] = f2bf_bits(tile[tx][ty + i * 8]);
}

// ---------------------------------------------------------------------------
// fp32 -> bf16 flat convert (4 elems/thread)
// ---------------------------------------------------------------------------
__global__ __launch_bounds__(256)
void cvt_kernel(const float* __restrict__ in, u16* __restrict__ out, int n4)
{
    int i = blockIdx.x * 256 + threadIdx.x;
    if (i >= n4) return;
    float4 v = ((const float4*)in)[i];
    ushort4 o;
    o.x = f2bf_bits(v.x); o.y = f2bf_bits(v.y);
    o.z = f2bf_bits(v.z); o.w = f2bf_bits(v.w);
    ((ushort4*)out)[i] = o;
}

// ---------------------------------------------------------------------------
// bf16 MFMA GEMM (m97 structure): C[M,N] = epi(A[M,K] @ Bt[N,K]^T + bias)
// BN = 128 or 64 (N-tile). 128xBN tile, BK=64, 256 threads = 4 waves (2x2).
// QKV_SPLIT: N=1536; cols [0,1024) -> Cout [M,1024] bf16 (q,k);
//            cols [1024,1536) -> Vout transposed vtb[b, d(512), t] bf16.
// ---------------------------------------------------------------------------
template<int BN, bool GELU_ACT, bool RESID, bool OUTBF16, bool QKV_SPLIT>
__global__ __launch_bounds__(256)
void mfma_gemm(const u16* __restrict__ A, const u16* __restrict__ Bt,
               const float* __restrict__ bias, const float* __restrict__ resid,
               void* __restrict__ Cout, u16* __restrict__ Vout,
               int M, int N, int K)
{
    constexpr int NJ = BN / 32;                 // j-fragments per wave
    __shared__ u16 As[128 * 64];
    __shared__ u16 Bs[BN * 64];

    const int tid  = threadIdx.x;
    const int lane = tid & 63;
    const int w    = tid >> 6;
    const int wr   = w >> 1, wc = w & 1;

    const int nbx = gridDim.x;
    const int nwg = nbx * gridDim.y;
    int bid = blockIdx.y * nbx + blockIdx.x;
    int swz = (bid & 7) * (nwg >> 3) + (bid >> 3);
    const int m0 = (swz / nbx) * 128;
    const int n0 = (swz % nbx) * BN;

    const int trow = tid >> 3;
    const int tcol = (tid & 7) * 8;
    const u16* ga = A  + (size_t)(m0 + trow) * K + tcol;
    const u16* gb = Bt + (size_t)(n0 + trow) * K + tcol;
    u16* la = As + tid * 8;
    u16* lb = Bs + tid * 8;

    f32x4 acc[4][NJ] = {};

    const int fr = lane & 15;
    const int fk = (lane >> 4) * 8;

    for (int k0 = 0; k0 < K; k0 += 64) {
        #pragma unroll
        for (int p = 0; p < 4; ++p)
            gll16(ga + k0 + (size_t)p * 32 * K, la + p * 2048);
        #pragma unroll
        for (int p = 0; p < NJ; ++p)
            gll16(gb + k0 + (size_t)p * 32 * K, lb + p * 2048);
        asm volatile("s_waitcnt vmcnt(0)" ::: "memory");
        __syncthreads();

        #pragma unroll
        for (int ks = 0; ks < 2; ++ks) {
            short8 af[4], bfr[NJ];
            #pragma unroll
            for (int f = 0; f < 4; ++f)
                af[f]  = *(const short8*)&As[(wr * 64 + f * 16 + fr) * 64 + ks * 32 + fk];
            #pragma unroll
            for (int f = 0; f < NJ; ++f)
                bfr[f] = *(const short8*)&Bs[(wc * (BN / 2) + f * 16 + fr) * 64 + ks * 32 + fk];
            #pragma unroll
            for (int i = 0; i < 4; ++i)
                #pragma unroll
                for (int j = 0; j < NJ; ++j)
                    acc[i][j] = __builtin_amdgcn_mfma_f32_16x16x32_bf16(
                        af[i], bfr[j], acc[i][j], 0, 0, 0);
        }
        __syncthreads();
    }

    const int c0 = n0 + wc * (BN / 2) + fr;
    const int r0 = m0 + wr * 64 + ((lane >> 4) << 2);
    #pragma unroll
    for (int j = 0; j < NJ; ++j) {
        const int c = c0 + j * 16;
        const float bv = bias ? bias[c] : 0.0f;
        #pragma unroll
        for (int i = 0; i < 4; ++i) {
            #pragma unroll
            for (int r = 0; r < 4; ++r) {
                const int row = r0 + i * 16 + r;
                float v = acc[i][j][r] + bv;
                if constexpr (GELU_ACT) v = gelu_exact(v);
                if constexpr (RESID) v += resid[(size_t)row * N + c];
                if constexpr (QKV_SPLIT) {
                    if (c < 1024) {
                        ((u16*)Cout)[(size_t)row * 1024 + c] = f2bf_bits(v);
                    } else {
                        // vtb[(b*512 + (c-1024)) * T + t]
                        const int t = row & (TT - 1);
                        Vout[(((size_t)(row >> 11) * 512 + (c - 1024)) << 11) + t] = f2bf_bits(v);
                    }
                } else if constexpr (OUTBF16) {
                    ((u16*)Cout)[(size_t)row * N + c] = f2bf_bits(v);
                } else {
                    ((float*)Cout)[(size_t)row * N + c] = v;
                }
            }
        }
    }
}

// ---------------------------------------------------------------------------
// bf16 MFMA flash attention. 512 flat blocks, 256 threads (4 waves).
// qkb: bf16 [M,1024] (q at +0, k at +512, head at h*64).
// vtb: bf16 [B][512=h*64+d][T]  (V pre-transposed by qkv GEMM epilogue).
// Block -> (qt,bh) CU-pairing remap for uniform causal work.
// ---------------------------------------------------------------------------
__global__ __launch_bounds__(256)
void attn_kernel(const u16* __restrict__ qkb, const u16* __restrict__ vtb,
                 u16* __restrict__ y)
{
    const int l = blockIdx.x;
    const int u = l & 255, v = l >> 8;
    const int bh = u & 15;
    const int half = u >> 4;
    const int qt = v ? (16 + half) : (15 - half);
    const int h = bh & (HH - 1);
    const int b = bh >> 3;

    __shared__ alignas(16) u16 Qs[64 * 64];
    __shared__ alignas(16) u16 Ks[64 * 64];
    __shared__ alignas(16) u16 Vt[64 * 64];   // [d][kv]
    __shared__ alignas(16) u16 Ps[64 * 64];

    const int tid = threadIdx.x;
    const int lane = tid & 63;
    const int w = tid >> 6;
    const int ln = lane & 15, hi = lane >> 4;
    const int q0 = qt * 64;

    const u16* base  = qkb + (size_t)b * TT * 1024 + h * HD;
    const u16* vbase = vtb + (size_t)(b * 512 + h * HD) * TT;

    // ---- stage Q (bf16, swizzled) ----
    {
        int r = tid >> 2, c0 = (tid & 3) * 16;
        const u16* qrow = base + (size_t)(q0 + r) * 1024;
        *(short8*)swp(Qs, r, c0)     = *(const short8*)(qrow + c0);
        *(short8*)swp(Qs, r, c0 + 8) = *(const short8*)(qrow + c0 + 8);
    }

    float m[4], lsum[4];
    f32x4 oacc[4] = {};
    #pragma unroll
    for (int r = 0; r < 4; ++r) { m[r] = -INFINITY; lsum[r] = 0.0f; }

    for (int kt = 0; kt <= qt; ++kt) {
        const int k0 = kt * 64;
        __syncthreads();                      // prev tile consumed (also Q staged)
        {
            int r = tid >> 2, c0 = (tid & 3) * 16;
            const u16* krow = base + (size_t)(k0 + r) * 1024 + 512;
            *(short8*)swp(Ks, r, c0)     = *(const short8*)(krow + c0);
            *(short8*)swp(Ks, r, c0 + 8) = *(const short8*)(krow + c0 + 8);
            const u16* vrow = vbase + (size_t)r * TT + k0;   // row r = head-dim d
            *(short8*)swp(Vt, r, c0)     = *(const short8*)(vrow + c0);
            *(short8*)swp(Vt, r, c0 + 8) = *(const short8*)(vrow + c0 + 8);
        }
        __syncthreads();

        // ---- S = Q K^T ----
        short8 aq[2];
        #pragma unroll
        for (int ks = 0; ks < 2; ++ks)
            aq[ks] = *(const short8*)swpc(Qs, w * 16 + ln, ks * 32 + hi * 8);

        f32x4 sacc[4] = {};
        #pragma unroll
        for (int j = 0; j < 4; ++j)
            #pragma unroll
            for (int ks = 0; ks < 2; ++ks) {
                short8 bk = *(const short8*)swpc(Ks, j * 16 + ln, ks * 32 + hi * 8);
                sacc[j] = __builtin_amdgcn_mfma_f32_16x16x32_bf16(aq[ks], bk, sacc[j], 0, 0, 0);
            }

        // ---- online softmax (fp32) ----
        const bool diag = (kt == qt);
        #pragma unroll
        for (int r = 0; r < 4; ++r) {
            const int qrow = w * 16 + hi * 4 + r;
            float sv[4];
            #pragma unroll
            for (int j = 0; j < 4; ++j) {
                float s = sacc[j][r] * 0.125f;
                if (diag && (j * 16 + ln > qrow)) s = -INFINITY;
                sv[j] = s;
            }
            float rm = fmaxf(fmaxf(sv[0], sv[1]), fmaxf(sv[2], sv[3]));
            #pragma unroll
            for (int o = 1; o < 16; o <<= 1) rm = fmaxf(rm, __shfl_xor(rm, o));
            float mn = fmaxf(m[r], rm);
            float corr = __expf(m[r] - mn);
            m[r] = mn;
            float ps = 0.0f;
            #pragma unroll
            for (int j = 0; j < 4; ++j) {
                float p = __expf(sv[j] - mn);
                ps += p;
                *swp(Ps, qrow, j * 16 + ln) = f2bf_bits(p);
            }
            #pragma unroll
            for (int o = 1; o < 16; o <<= 1) ps += __shfl_xor(ps, o);
            lsum[r] = lsum[r] * corr + ps;
            #pragma unroll
            for (int db = 0; db < 4; ++db) oacc[db][r] *= corr;
        }

        // ---- O += P V ----
        short8 ap[2];
        #pragma unroll
        for (int ks = 0; ks < 2; ++ks)
            ap[ks] = *(const short8*)swpc(Ps, w * 16 + ln, ks * 32 + hi * 8);
        #pragma unroll
        for (int db = 0; db < 4; ++db)
            #pragma unroll
            for (int ks = 0; ks < 2; ++ks) {
                short8 bv = *(const short8*)swpc(Vt, db * 16 + ln, ks * 32 + hi * 8);
                oacc[db] = __builtin_amdgcn_mfma_f32_16x16x32_bf16(ap[ks], bv, oacc[db], 0, 0, 0);
            }
    }

    // ---- epilogue ----
    #pragma unroll
    for (int r = 0; r < 4; ++r) {
        const int q = q0 + w * 16 + hi * 4 + r;
        const float inv = 1.0f / lsum[r];
        u16* yrow = y + (size_t)(b * TT + q) * DD + h * HD;
        #pragma unroll
        for (int db = 0; db < 4; ++db)
            yrow[db * 16 + ln] = f2bf_bits(oacc[db][r] * inv);
    }
}

// ---------------------------------------------------------------------------
// Host-side launch
// ---------------------------------------------------------------------------
extern "C" void kernel_launch(void* const* d_in, const int* in_sizes, int n_in,
                              void* d_out, int out_size, void* d_ws, size_t ws_size,
                              hipStream_t stream)
{
    const int*   idx    = (const int*)  d_in[0];
    const float* wte    = (const float*)d_in[1];
    const float* wpe    = (const float*)d_in[2];
    const float* ln1_g  = (const float*)d_in[3];
    const float* ln1_b  = (const float*)d_in[4];
    const float* qkv_w  = (const float*)d_in[5];
    const float* qkv_b  = (const float*)d_in[6];
    const float* proj_w = (const float*)d_in[7];
    const float* proj_b = (const float*)d_in[8];
    const float* ln2_g  = (const float*)d_in[9];
    const float* ln2_b  = (const float*)d_in[10];
    const float* fc1_w  = (const float*)d_in[11];
    const float* fc1_b  = (const float*)d_in[12];
    const float* fc2_w  = (const float*)d_in[13];
    const float* fc2_b  = (const float*)d_in[14];
    const float* lnf_g  = (const float*)d_in[15];
    const float* lnf_b  = (const float*)d_in[16];
    float* out = (float*)d_out;

    // workspace layout (MB offsets)
    char* ws = (char*)d_ws;
    float* x    = (float*)(ws);                       // [M,D] fp32      8 MB
    u16*   h    = (u16*)(ws + ((size_t)8  << 20));    // [M,D] bf16      4 MB
    u16*   y    = (u16*)(ws + ((size_t)12 << 20));    // [M,D] bf16      4 MB
    u16*   qkb  = (u16*)(ws + ((size_t)16 << 20));    // [M,1024] bf16   8 MB
    u16*   vtb  = (u16*)(ws + ((size_t)24 << 20));    // [B,512,T] bf16  4 MB
    u16*   wqa  = (u16*)(ws + ((size_t)28 << 20));    // 6*[1536,512]    9.4 MB
    u16*   wpa  = (u16*)(ws + ((size_t)38 << 20));    // 6*[512,512]     3.2 MB
    u16*   w1a  = (u16*)(ws + ((size_t)42 << 20));    // 6*[2048,512]   12.6 MB
    u16*   w2a  = (u16*)(ws + ((size_t)55 << 20));    // 6*[512,2048]   12.6 MB
    u16*   ffb  = (u16*)(ws + ((size_t)68 << 20));    // [M,F] bf16     16.8 MB
    u16*   wteb = (u16*)(ws + ((size_t)85 << 20));    // [V,D] bf16     32.8 MB

    embed_kernel<<<MM, 128, 0, stream>>>(idx, wte, wpe, x);

    weight_prep_kernel<<<LL * 3072, 256, 0, stream>>>(
        qkv_w, proj_w, fc1_w, fc2_w, wqa, wpa, w1a, w2a);

    cvt_kernel<<<(VV * DD / 4 + 255) / 256, 256, 0, stream>>>(wte, wteb, VV * DD / 4);

    for (int l = 0; l < LL; ++l) {
        ln_kernel<<<MM, 256, 0, stream>>>(x, ln1_g + l * DD, ln1_b + l * DD, h);

        mfma_gemm<128, false, false, true, true><<<dim3(12, 32), 256, 0, stream>>>(
            h, wqa + (size_t)l * 3 * DD * DD, qkv_b + (size_t)l * 3 * DD,
            nullptr, qkb, vtb, MM, 3 * DD, DD);

        attn_kernel<<<512, 256, 0, stream>>>(qkb, vtb, y);

        mfma_gemm<64, false, true, false, false><<<dim3(8, 32), 256, 0, stream>>>(
            y, wpa + (size_t)l * DD * DD, proj_b + (size_t)l * DD,
            x, x, nullptr, MM, DD, DD);

        ln_kernel<<<MM, 256, 0, stream>>>(x, ln2_g + l * DD, ln2_b + l * DD, h);

        mfma_gemm<128, true, false, true, false><<<dim3(16, 32), 256, 0, stream>>>(
            h, w1a + (size_t)l * DD * FF, fc1_b + (size_t)l * FF,
            nullptr, ffb, nullptr, MM, FF, DD);

        mfma_gemm<64, false, true, false, false><<<dim3(8, 32), 256, 0, stream>>>(
            ffb, w2a + (size_t)l * FF * DD, fc2_b + (size_t)l * DD,
            x, x, nullptr, MM, DD, FF);
    }

    ln_kernel<<<MM, 256, 0, stream>>>(x, lnf_g, lnf_b, h);

    mfma_gemm<128, false, false, false, false><<<dim3(250, 32), 256, 0, stream>>>(
        h, wteb, nullptr, nullptr, out, nullptr, MM, VV, DD);
}

// Round 6
// 1194.955 us; speedup vs baseline: 26.4324x; 1.0443x over previous
//
#include <hip/hip_runtime.h>
#include <hip/hip_bf16.h>
#include <math.h>

// Problem constants
#define BB 2
#define TT 2048
#define DD 512
#define HH 8
#define HD 64
#define FF 2048
#define VV 32000
#define LL 6
#define MM (BB * TT)   // 4096

typedef unsigned int   u32;
typedef unsigned short u16;
typedef __attribute__((ext_vector_type(8))) short short8;   // bf16x8 frag (4 VGPR)
typedef __attribute__((ext_vector_type(4))) float f32x4;    // acc frag

__device__ __forceinline__ u16 f2bf_bits(float f)
{
    __hip_bfloat16 h = __float2bfloat16(f);   // RNE
    u16 u;
    __builtin_memcpy(&u, &h, 2);
    return u;
}

__device__ __forceinline__ void gll16(const u16* g, u16* l)
{
    __builtin_amdgcn_global_load_lds(
        (const __attribute__((address_space(1))) u32*)g,
        (__attribute__((address_space(3))) u32*)l,
        16, 0, 0);
}

__device__ __forceinline__ float gelu_exact(float v)
{
    return 0.5f * v * (1.0f + erff(v * 0.70710678118654752440f));
}

// XOR-swizzled pointer into a [64][64]-u16 LDS tile (row = 128 B).
__device__ __forceinline__ u16* swp(u16* base, int row, int col)
{
    int off = (row * 128 + col * 2) ^ ((row & 7) << 4);
    return (u16*)((char*)base + off);
}
__device__ __forceinline__ const u16* swpc(const u16* base, int row, int col)
{
    int off = (row * 128 + col * 2) ^ ((row & 7) << 4);
    return (const u16*)((const char*)base + off);
}

// ---------------------------------------------------------------------------
// Embedding: x[b,t,:] = wte[idx[b,t],:] + wpe[t,:]   (fp32 out)
// ---------------------------------------------------------------------------
__global__ __launch_bounds__(128)
void embed_kernel(const int* __restrict__ idx, const float* __restrict__ wte,
                  const float* __restrict__ wpe, float* __restrict__ x)
{
    int row = blockIdx.x;
    int t = row & (TT - 1);
    int tok = idx[row];
    const float4* wt = (const float4*)(wte + (size_t)tok * DD);
    const float4* wp = (const float4*)(wpe + (size_t)t * DD);
    float4 a = wt[threadIdx.x];
    float4 p = wp[threadIdx.x];
    float4 r;
    r.x = a.x + p.x; r.y = a.y + p.y; r.z = a.z + p.z; r.w = a.w + p.w;
    ((float4*)(x + (size_t)row * DD))[threadIdx.x] = r;
}

// ---------------------------------------------------------------------------
// LayerNorm (fp32 in, bf16 out). 1 block (256 threads) per row of 512.
// ---------------------------------------------------------------------------
__global__ __launch_bounds__(256)
void ln_kernel(const float* __restrict__ x, const float* __restrict__ g,
               const float* __restrict__ b, u16* __restrict__ out)
{
    int row = blockIdx.x;
    const float* xr = x + (size_t)row * DD;
    int tid = threadIdx.x;
    float v1 = xr[tid], v2 = xr[tid + 256];
    float s = v1 + v2;
    float ss = v1 * v1 + v2 * v2;
    #pragma unroll
    for (int o = 32; o; o >>= 1) {
        s  += __shfl_xor(s, o);
        ss += __shfl_xor(ss, o);
    }
    __shared__ float sred[4], ssred[4];
    int wid = tid >> 6, lane = tid & 63;
    if (lane == 0) { sred[wid] = s; ssred[wid] = ss; }
    __syncthreads();
    s  = sred[0] + sred[1] + sred[2] + sred[3];
    ss = ssred[0] + ssred[1] + ssred[2] + ssred[3];
    float mu  = s * (1.0f / DD);
    float var = ss * (1.0f / DD) - mu * mu;
    float rs  = rsqrtf(var + 1e-5f);
    u16* orow = out + (size_t)row * DD;
    orow[tid]       = f2bf_bits((v1 - mu) * rs * g[tid]       + b[tid]);
    orow[tid + 256] = f2bf_bits((v2 - mu) * rs * g[tid + 256] + b[tid + 256]);
}

// ---------------------------------------------------------------------------
// Weight prep: ALL layers' fp32 [K,N] -> bf16 [N,K] transposes in one launch.
// ---------------------------------------------------------------------------
__global__ __launch_bounds__(256)
void weight_prep_kernel(const float* __restrict__ qkv_w, const float* __restrict__ proj_w,
                        const float* __restrict__ fc1_w, const float* __restrict__ fc2_w,
                        u16* __restrict__ wqa, u16* __restrict__ wpa,
                        u16* __restrict__ w1a, u16* __restrict__ w2a)
{
    int id = blockIdx.x;
    int l = id / 3072, r = id % 3072;
    const float* in; u16* out; int K, N, tt;
    if (r < 768)       { in = qkv_w + (size_t)l * DD * 3 * DD; out = wqa + (size_t)l * 3 * DD * DD; K = DD; N = 3 * DD; tt = r; }
    else if (r < 1024) { in = proj_w + (size_t)l * DD * DD;    out = wpa + (size_t)l * DD * DD;    K = DD; N = DD;     tt = r - 768; }
    else if (r < 2048) { in = fc1_w + (size_t)l * DD * FF;     out = w1a + (size_t)l * DD * FF;    K = DD; N = FF;     tt = r - 1024; }
    else               { in = fc2_w + (size_t)l * FF * DD;     out = w2a + (size_t)l * FF * DD;    K = FF; N = DD;     tt = r - 2048; }
    int ntx = N >> 5;
    int n0 = (tt % ntx) << 5, k0 = (tt / ntx) << 5;
    __shared__ float tile[32][33];
    int tx = threadIdx.x & 31, ty = threadIdx.x >> 5;
    #pragma unroll
    for (int i = 0; i < 4; ++i)
        tile[ty + i * 8][tx] = in[(size_t)(k0 + ty + i * 8) * N + n0 + tx];
    __syncthreads();
    #pragma unroll
    for (int i = 0; i < 4; ++i)
        out[(size_t)(n0 + ty + i * 8) * K + k0 + tx] = f2bf_bits(tile[tx][ty + i * 8]);
}

// ---------------------------------------------------------------------------
// fp32 -> bf16 flat convert (4 elems/thread)
// ---------------------------------------------------------------------------
__global__ __launch_bounds__(256)
void cvt_kernel(const float* __restrict__ in, u16* __restrict__ out, int n4)
{
    int i = blockIdx.x * 256 + threadIdx.x;
    if (i >= n4) return;
    float4 v = ((const float4*)in)[i];
    ushort4 o;
    o.x = f2bf_bits(v.x); o.y = f2bf_bits(v.y);
    o.z = f2bf_bits(v.z); o.w = f2bf_bits(v.w);
    ((ushort4*)out)[i] = o;
}

// ---------------------------------------------------------------------------
// bf16 MFMA GEMM (m97 structure): C[M,N] = epi(A[M,K] @ Bt[N,K]^T + bias)
// ---------------------------------------------------------------------------
template<int BN, bool GELU_ACT, bool RESID, bool OUTBF16, bool QKV_SPLIT>
__global__ __launch_bounds__(256)
void mfma_gemm(const u16* __restrict__ A, const u16* __restrict__ Bt,
               const float* __restrict__ bias, const float* __restrict__ resid,
               void* __restrict__ Cout, u16* __restrict__ Vout,
               int M, int N, int K)
{
    constexpr int NJ = BN / 32;
    __shared__ u16 As[128 * 64];
    __shared__ u16 Bs[BN * 64];

    const int tid  = threadIdx.x;
    const int lane = tid & 63;
    const int w    = tid >> 6;
    const int wr   = w >> 1, wc = w & 1;

    const int nbx = gridDim.x;
    const int nwg = nbx * gridDim.y;
    int bid = blockIdx.y * nbx + blockIdx.x;
    int swz = (bid & 7) * (nwg >> 3) + (bid >> 3);
    const int m0 = (swz / nbx) * 128;
    const int n0 = (swz % nbx) * BN;

    const int trow = tid >> 3;
    const int tcol = (tid & 7) * 8;
    const u16* ga = A  + (size_t)(m0 + trow) * K + tcol;
    const u16* gb = Bt + (size_t)(n0 + trow) * K + tcol;
    u16* la = As + tid * 8;
    u16* lb = Bs + tid * 8;

    f32x4 acc[4][NJ] = {};

    const int fr = lane & 15;
    const int fk = (lane >> 4) * 8;

    for (int k0 = 0; k0 < K; k0 += 64) {
        #pragma unroll
        for (int p = 0; p < 4; ++p)
            gll16(ga + k0 + (size_t)p * 32 * K, la + p * 2048);
        #pragma unroll
        for (int p = 0; p < NJ; ++p)
            gll16(gb + k0 + (size_t)p * 32 * K, lb + p * 2048);
        asm volatile("s_waitcnt vmcnt(0)" ::: "memory");
        __syncthreads();

        #pragma unroll
        for (int ks = 0; ks < 2; ++ks) {
            short8 af[4], bfr[NJ];
            #pragma unroll
            for (int f = 0; f < 4; ++f)
                af[f]  = *(const short8*)&As[(wr * 64 + f * 16 + fr) * 64 + ks * 32 + fk];
            #pragma unroll
            for (int f = 0; f < NJ; ++f)
                bfr[f] = *(const short8*)&Bs[(wc * (BN / 2) + f * 16 + fr) * 64 + ks * 32 + fk];
            #pragma unroll
            for (int i = 0; i < 4; ++i)
                #pragma unroll
                for (int j = 0; j < NJ; ++j)
                    acc[i][j] = __builtin_amdgcn_mfma_f32_16x16x32_bf16(
                        af[i], bfr[j], acc[i][j], 0, 0, 0);
        }
        __syncthreads();
    }

    const int c0 = n0 + wc * (BN / 2) + fr;
    const int r0 = m0 + wr * 64 + ((lane >> 4) << 2);
    #pragma unroll
    for (int j = 0; j < NJ; ++j) {
        const int c = c0 + j * 16;
        const float bv = bias ? bias[c] : 0.0f;
        #pragma unroll
        for (int i = 0; i < 4; ++i) {
            #pragma unroll
            for (int r = 0; r < 4; ++r) {
                const int row = r0 + i * 16 + r;
                float v = acc[i][j][r] + bv;
                if constexpr (GELU_ACT) v = gelu_exact(v);
                if constexpr (RESID) v += resid[(size_t)row * N + c];
                if constexpr (QKV_SPLIT) {
                    if (c < 1024) {
                        ((u16*)Cout)[(size_t)row * 1024 + c] = f2bf_bits(v);
                    } else {
                        const int t = row & (TT - 1);
                        Vout[(((size_t)(row >> 11) * 512 + (c - 1024)) << 11) + t] = f2bf_bits(v);
                    }
                } else if constexpr (OUTBF16) {
                    ((u16*)Cout)[(size_t)row * N + c] = f2bf_bits(v);
                } else {
                    ((float*)Cout)[(size_t)row * N + c] = v;
                }
            }
        }
    }
}

// ---------------------------------------------------------------------------
// bf16 MFMA flash attention, double-buffered K/V + issue-early reg staging.
// 512 flat blocks, 256 threads (4 waves). One __syncthreads per k-tile:
//   ds_write buf[t&1] <- regs(t); sync; issue loads(t+1); compute(t)
// Loads for t+1 fly during compute(t); their vmcnt wait lands at the next
// tile's ds_write (fully hidden). Two buffers make the single barrier safe.
// qkb: bf16 [M,1024] (q at +0, k at +512); vtb: bf16 [B][512][T].
// ---------------------------------------------------------------------------
__global__ __launch_bounds__(256)
void attn_kernel(const u16* __restrict__ qkb, const u16* __restrict__ vtb,
                 u16* __restrict__ y)
{
    const int l = blockIdx.x;
    const int u = l & 255, v = l >> 8;
    const int bh = u & 15;
    const int half = u >> 4;
    const int qt = v ? (16 + half) : (15 - half);
    const int h = bh & (HH - 1);
    const int b = bh >> 3;

    __shared__ alignas(16) u16 Qs[4096];
    __shared__ alignas(16) u16 Ks[2][4096];
    __shared__ alignas(16) u16 Vt[2][4096];   // [d][kv]
    __shared__ alignas(16) u16 Ps[4096];

    const int tid = threadIdx.x;
    const int lane = tid & 63;
    const int w = tid >> 6;
    const int ln = lane & 15, hi = lane >> 4;
    const int q0 = qt * 64;

    const u16* base  = qkb + (size_t)b * TT * 1024 + h * HD;
    const u16* vbase = vtb + (size_t)(b * 512 + h * HD) * TT;

    const int sr = tid >> 2, sc = (tid & 3) * 16;   // staging row/col

    // ---- stage Q (bf16, swizzled) + first K/V tile into regs ----
    {
        const u16* qrow = base + (size_t)(q0 + sr) * 1024;
        *(short8*)swp(Qs, sr, sc)     = *(const short8*)(qrow + sc);
        *(short8*)swp(Qs, sr, sc + 8) = *(const short8*)(qrow + sc + 8);
    }
    short8 rk0, rk1, rv0, rv1;
    {
        const u16* krow = base + (size_t)sr * 1024 + 512;
        rk0 = *(const short8*)(krow + sc);
        rk1 = *(const short8*)(krow + sc + 8);
        const u16* vrow = vbase + (size_t)sr * TT;
        rv0 = *(const short8*)(vrow + sc);
        rv1 = *(const short8*)(vrow + sc + 8);
    }

    float m[4], lsum[4];
    f32x4 oacc[4] = {};
    #pragma unroll
    for (int r = 0; r < 4; ++r) { m[r] = -INFINITY; lsum[r] = 0.0f; }

    for (int kt = 0; kt <= qt; ++kt) {
        u16* ks = Ks[kt & 1];
        u16* vt = Vt[kt & 1];

        // ---- write staged regs to LDS (vmcnt wait here is a tile old) ----
        *(short8*)swp(ks, sr, sc)     = rk0;
        *(short8*)swp(ks, sr, sc + 8) = rk1;
        *(short8*)swp(vt, sr, sc)     = rv0;
        *(short8*)swp(vt, sr, sc + 8) = rv1;
        __syncthreads();

        // ---- issue next tile's loads (fly during compute below) ----
        if (kt < qt) {
            const int k0n = (kt + 1) * 64;
            const u16* krow = base + (size_t)(k0n + sr) * 1024 + 512;
            rk0 = *(const short8*)(krow + sc);
            rk1 = *(const short8*)(krow + sc + 8);
            const u16* vrow = vbase + (size_t)sr * TT + k0n;
            rv0 = *(const short8*)(vrow + sc);
            rv1 = *(const short8*)(vrow + sc + 8);
        }

        // ---- S = Q K^T ----
        short8 aq[2];
        #pragma unroll
        for (int s2 = 0; s2 < 2; ++s2)
            aq[s2] = *(const short8*)swpc(Qs, w * 16 + ln, s2 * 32 + hi * 8);

        f32x4 sacc[4] = {};
        __builtin_amdgcn_s_setprio(1);
        #pragma unroll
        for (int j = 0; j < 4; ++j)
            #pragma unroll
            for (int s2 = 0; s2 < 2; ++s2) {
                short8 bk = *(const short8*)swpc(ks, j * 16 + ln, s2 * 32 + hi * 8);
                sacc[j] = __builtin_amdgcn_mfma_f32_16x16x32_bf16(aq[s2], bk, sacc[j], 0, 0, 0);
            }
        __builtin_amdgcn_s_setprio(0);

        // ---- online softmax (fp32) ----
        const bool diag = (kt == qt);
        #pragma unroll
        for (int r = 0; r < 4; ++r) {
            const int qrow = w * 16 + hi * 4 + r;
            float sv[4];
            #pragma unroll
            for (int j = 0; j < 4; ++j) {
                float s = sacc[j][r] * 0.125f;
                if (diag && (j * 16 + ln > qrow)) s = -INFINITY;
                sv[j] = s;
            }
            float rm = fmaxf(fmaxf(sv[0], sv[1]), fmaxf(sv[2], sv[3]));
            #pragma unroll
            for (int o = 1; o < 16; o <<= 1) rm = fmaxf(rm, __shfl_xor(rm, o));
            float mn = fmaxf(m[r], rm);
            float corr = __expf(m[r] - mn);
            m[r] = mn;
            float ps = 0.0f;
            #pragma unroll
            for (int j = 0; j < 4; ++j) {
                float p = __expf(sv[j] - mn);
                ps += p;
                *swp(Ps, qrow, j * 16 + ln) = f2bf_bits(p);
            }
            #pragma unroll
            for (int o = 1; o < 16; o <<= 1) ps += __shfl_xor(ps, o);
            lsum[r] = lsum[r] * corr + ps;
            #pragma unroll
            for (int db = 0; db < 4; ++db) oacc[db][r] *= corr;
        }

        // ---- O += P V (Ps rows are wave-private; no barrier needed) ----
        short8 ap[2];
        #pragma unroll
        for (int s2 = 0; s2 < 2; ++s2)
            ap[s2] = *(const short8*)swpc(Ps, w * 16 + ln, s2 * 32 + hi * 8);
        __builtin_amdgcn_s_setprio(1);
        #pragma unroll
        for (int db = 0; db < 4; ++db)
            #pragma unroll
            for (int s2 = 0; s2 < 2; ++s2) {
                short8 bv = *(const short8*)swpc(vt, db * 16 + ln, s2 * 32 + hi * 8);
                oacc[db] = __builtin_amdgcn_mfma_f32_16x16x32_bf16(ap[s2], bv, oacc[db], 0, 0, 0);
            }
        __builtin_amdgcn_s_setprio(0);
    }

    // ---- epilogue ----
    #pragma unroll
    for (int r = 0; r < 4; ++r) {
        const int q = q0 + w * 16 + hi * 4 + r;
        const float inv = 1.0f / lsum[r];
        u16* yrow = y + (size_t)(b * TT + q) * DD + h * HD;
        #pragma unroll
        for (int db = 0; db < 4; ++db)
            yrow[db * 16 + ln] = f2bf_bits(oacc[db][r] * inv);
    }
}

// ---------------------------------------------------------------------------
// Host-side launch
// ---------------------------------------------------------------------------
extern "C" void kernel_launch(void* const* d_in, const int* in_sizes, int n_in,
                              void* d_out, int out_size, void* d_ws, size_t ws_size,
                              hipStream_t stream)
{
    const int*   idx    = (const int*)  d_in[0];
    const float* wte    = (const float*)d_in[1];
    const float* wpe    = (const float*)d_in[2];
    const float* ln1_g  = (const float*)d_in[3];
    const float* ln1_b  = (const float*)d_in[4];
    const float* qkv_w  = (const float*)d_in[5];
    const float* qkv_b  = (const float*)d_in[6];
    const float* proj_w = (const float*)d_in[7];
    const float* proj_b = (const float*)d_in[8];
    const float* ln2_g  = (const float*)d_in[9];
    const float* ln2_b  = (const float*)d_in[10];
    const float* fc1_w  = (const float*)d_in[11];
    const float* fc1_b  = (const float*)d_in[12];
    const float* fc2_w  = (const float*)d_in[13];
    const float* fc2_b  = (const float*)d_in[14];
    const float* lnf_g  = (const float*)d_in[15];
    const float* lnf_b  = (const float*)d_in[16];
    float* out = (float*)d_out;

    char* ws = (char*)d_ws;
    float* x    = (float*)(ws);                       // [M,D] fp32      8 MB
    u16*   h    = (u16*)(ws + ((size_t)8  << 20));    // [M,D] bf16      4 MB
    u16*   y    = (u16*)(ws + ((size_t)12 << 20));    // [M,D] bf16      4 MB
    u16*   qkb  = (u16*)(ws + ((size_t)16 << 20));    // [M,1024] bf16   8 MB
    u16*   vtb  = (u16*)(ws + ((size_t)24 << 20));    // [B,512,T] bf16  4 MB
    u16*   wqa  = (u16*)(ws + ((size_t)28 << 20));    // 6*[1536,512]    9.4 MB
    u16*   wpa  = (u16*)(ws + ((size_t)38 << 20));    // 6*[512,512]     3.2 MB
    u16*   w1a  = (u16*)(ws + ((size_t)42 << 20));    // 6*[2048,512]   12.6 MB
    u16*   w2a  = (u16*)(ws + ((size_t)55 << 20));    // 6*[512,2048]   12.6 MB
    u16*   ffb  = (u16*)(ws + ((size_t)68 << 20));    // [M,F] bf16     16.8 MB
    u16*   wteb = (u16*)(ws + ((size_t)85 << 20));    // [V,D] bf16     32.8 MB

    embed_kernel<<<MM, 128, 0, stream>>>(idx, wte, wpe, x);

    weight_prep_kernel<<<LL * 3072, 256, 0, stream>>>(
        qkv_w, proj_w, fc1_w, fc2_w, wqa, wpa, w1a, w2a);

    cvt_kernel<<<(VV * DD / 4 + 255) / 256, 256, 0, stream>>>(wte, wteb, VV * DD / 4);

    for (int l = 0; l < LL; ++l) {
        ln_kernel<<<MM, 256, 0, stream>>>(x, ln1_g + l * DD, ln1_b + l * DD, h);

        mfma_gemm<128, false, false, true, true><<<dim3(12, 32), 256, 0, stream>>>(
            h, wqa + (size_t)l * 3 * DD * DD, qkv_b + (size_t)l * 3 * DD,
            nullptr, qkb, vtb, MM, 3 * DD, DD);

        attn_kernel<<<512, 256, 0, stream>>>(qkb, vtb, y);

        mfma_gemm<64, false, true, false, false><<<dim3(8, 32), 256, 0, stream>>>(
            y, wpa + (size_t)l * DD * DD, proj_b + (size_t)l * DD,
            x, x, nullptr, MM, DD, DD);

        ln_kernel<<<MM, 256, 0, stream>>>(x, ln2_g + l * DD, ln2_b + l * DD, h);

        mfma_gemm<128, true, false, true, false><<<dim3(16, 32), 256, 0, stream>>>(
            h, w1a + (size_t)l * DD * FF, fc1_b + (size_t)l * FF,
            nullptr, ffb, nullptr, MM, FF, DD);

        mfma_gemm<64, false, true, false, false><<<dim3(8, 32), 256, 0, stream>>>(
            ffb, w2a + (size_t)l * FF * DD, fc2_b + (size_t)l * DD,
            x, x, nullptr, MM, DD, FF);
    }

    ln_kernel<<<MM, 256, 0, stream>>>(x, lnf_g, lnf_b, h);

    mfma_gemm<128, false, false, false, false><<<dim3(250, 32), 256, 0, stream>>>(
        h, wteb, nullptr, nullptr, out, nullptr, MM, VV, DD);
}

// Round 7
// 1160.519 us; speedup vs baseline: 27.2167x; 1.0297x over previous
//
#include <hip/hip_runtime.h>
#include <hip/hip_bf16.h>
#include <math.h>

// Problem constants
#define BB 2
#define TT 2048
#define DD 512
#define HH 8
#define HD 64
#define FF 2048
#define VV 32000
#define LL 6
#define MM (BB * TT)   // 4096

typedef unsigned int   u32;
typedef unsigned short u16;
typedef __attribute__((ext_vector_type(8))) short short8;   // bf16x8 frag (4 VGPR)
typedef __attribute__((ext_vector_type(4))) float f32x4;    // acc frag

__device__ __forceinline__ u16 f2bf_bits(float f)
{
    __hip_bfloat16 h = __float2bfloat16(f);   // RNE
    u16 u;
    __builtin_memcpy(&u, &h, 2);
    return u;
}

__device__ __forceinline__ void gll16(const u16* g, u16* l)
{
    __builtin_amdgcn_global_load_lds(
        (const __attribute__((address_space(1))) u32*)g,
        (__attribute__((address_space(3))) u32*)l,
        16, 0, 0);
}

__device__ __forceinline__ float gelu_exact(float v)
{
    return 0.5f * v * (1.0f + erff(v * 0.70710678118654752440f));
}

// XOR-swizzled pointer into a [64][64]-u16 LDS tile (row = 128 B).
__device__ __forceinline__ u16* swp(u16* base, int row, int col)
{
    int off = (row * 128 + col * 2) ^ ((row & 7) << 4);
    return (u16*)((char*)base + off);
}
__device__ __forceinline__ const u16* swpc(const u16* base, int row, int col)
{
    int off = (row * 128 + col * 2) ^ ((row & 7) << 4);
    return (const u16*)((const char*)base + off);
}

// ---------------------------------------------------------------------------
// Embedding: x[b,t,:] = wte[idx[b,t],:] + wpe[t,:]   (fp32 out)
// ---------------------------------------------------------------------------
__global__ __launch_bounds__(128)
void embed_kernel(const int* __restrict__ idx, const float* __restrict__ wte,
                  const float* __restrict__ wpe, float* __restrict__ x)
{
    int row = blockIdx.x;
    int t = row & (TT - 1);
    int tok = idx[row];
    const float4* wt = (const float4*)(wte + (size_t)tok * DD);
    const float4* wp = (const float4*)(wpe + (size_t)t * DD);
    float4 a = wt[threadIdx.x];
    float4 p = wp[threadIdx.x];
    float4 r;
    r.x = a.x + p.x; r.y = a.y + p.y; r.z = a.z + p.z; r.w = a.w + p.w;
    ((float4*)(x + (size_t)row * DD))[threadIdx.x] = r;
}

// ---------------------------------------------------------------------------
// LayerNorm (fp32 in, bf16 out). 1 block (256 threads) per row of 512.
// ---------------------------------------------------------------------------
__global__ __launch_bounds__(256)
void ln_kernel(const float* __restrict__ x, const float* __restrict__ g,
               const float* __restrict__ b, u16* __restrict__ out)
{
    int row = blockIdx.x;
    const float* xr = x + (size_t)row * DD;
    int tid = threadIdx.x;
    float v1 = xr[tid], v2 = xr[tid + 256];
    float s = v1 + v2;
    float ss = v1 * v1 + v2 * v2;
    #pragma unroll
    for (int o = 32; o; o >>= 1) {
        s  += __shfl_xor(s, o);
        ss += __shfl_xor(ss, o);
    }
    __shared__ float sred[4], ssred[4];
    int wid = tid >> 6, lane = tid & 63;
    if (lane == 0) { sred[wid] = s; ssred[wid] = ss; }
    __syncthreads();
    s  = sred[0] + sred[1] + sred[2] + sred[3];
    ss = ssred[0] + ssred[1] + ssred[2] + ssred[3];
    float mu  = s * (1.0f / DD);
    float var = ss * (1.0f / DD) - mu * mu;
    float rs  = rsqrtf(var + 1e-5f);
    u16* orow = out + (size_t)row * DD;
    orow[tid]       = f2bf_bits((v1 - mu) * rs * g[tid]       + b[tid]);
    orow[tid + 256] = f2bf_bits((v2 - mu) * rs * g[tid + 256] + b[tid + 256]);
}

// ---------------------------------------------------------------------------
// Weight prep: ALL layers' fp32 [K,N] -> bf16 [N,K] transposes in one launch.
// ---------------------------------------------------------------------------
__global__ __launch_bounds__(256)
void weight_prep_kernel(const float* __restrict__ qkv_w, const float* __restrict__ proj_w,
                        const float* __restrict__ fc1_w, const float* __restrict__ fc2_w,
                        u16* __restrict__ wqa, u16* __restrict__ wpa,
                        u16* __restrict__ w1a, u16* __restrict__ w2a)
{
    int id = blockIdx.x;
    int l = id / 3072, r = id % 3072;
    const float* in; u16* out; int K, N, tt;
    if (r < 768)       { in = qkv_w + (size_t)l * DD * 3 * DD; out = wqa + (size_t)l * 3 * DD * DD; K = DD; N = 3 * DD; tt = r; }
    else if (r < 1024) { in = proj_w + (size_t)l * DD * DD;    out = wpa + (size_t)l * DD * DD;    K = DD; N = DD;     tt = r - 768; }
    else if (r < 2048) { in = fc1_w + (size_t)l * DD * FF;     out = w1a + (size_t)l * DD * FF;    K = DD; N = FF;     tt = r - 1024; }
    else               { in = fc2_w + (size_t)l * FF * DD;     out = w2a + (size_t)l * FF * DD;    K = FF; N = DD;     tt = r - 2048; }
    int ntx = N >> 5;
    int n0 = (tt % ntx) << 5, k0 = (tt / ntx) << 5;
    __shared__ float tile[32][33];
    int tx = threadIdx.x & 31, ty = threadIdx.x >> 5;
    #pragma unroll
    for (int i = 0; i < 4; ++i)
        tile[ty + i * 8][tx] = in[(size_t)(k0 + ty + i * 8) * N + n0 + tx];
    __syncthreads();
    #pragma unroll
    for (int i = 0; i < 4; ++i)
        out[(size_t)(n0 + ty + i * 8) * K + k0 + tx] = f2bf_bits(tile[tx][ty + i * 8]);
}

// ---------------------------------------------------------------------------
// fp32 -> bf16 flat convert (4 elems/thread)
// ---------------------------------------------------------------------------
__global__ __launch_bounds__(256)
void cvt_kernel(const float* __restrict__ in, u16* __restrict__ out, int n4)
{
    int i = blockIdx.x * 256 + threadIdx.x;
    if (i >= n4) return;
    float4 v = ((const float4*)in)[i];
    ushort4 o;
    o.x = f2bf_bits(v.x); o.y = f2bf_bits(v.y);
    o.z = f2bf_bits(v.z); o.w = f2bf_bits(v.w);
    ((ushort4*)out)[i] = o;
}

// ---------------------------------------------------------------------------
// bf16 MFMA GEMM, pipelined (T3-minimum): double-buffered LDS, stage(t+1)
// issued after the barrier and before compute(t); one vmcnt(0)+barrier/tile.
// C[M,N] = epi(A[M,K] @ Bt[N,K]^T + bias). BN = 128 or 64.
// ---------------------------------------------------------------------------
template<int BN, bool GELU_ACT, bool RESID, bool OUTBF16, bool QKV_SPLIT>
__global__ __launch_bounds__(256)
void mfma_gemm(const u16* __restrict__ A, const u16* __restrict__ Bt,
               const float* __restrict__ bias, const float* __restrict__ resid,
               void* __restrict__ Cout, u16* __restrict__ Vout,
               int M, int N, int K)
{
    constexpr int NJ = BN / 32;
    __shared__ u16 As[2][128 * 64];
    __shared__ u16 Bs[2][BN * 64];

    const int tid  = threadIdx.x;
    const int lane = tid & 63;
    const int w    = tid >> 6;
    const int wr   = w >> 1, wc = w & 1;

    const int nbx = gridDim.x;
    const int nwg = nbx * gridDim.y;
    int bid = blockIdx.y * nbx + blockIdx.x;
    int swz = (bid & 7) * (nwg >> 3) + (bid >> 3);
    const int m0 = (swz / nbx) * 128;
    const int n0 = (swz % nbx) * BN;

    const int trow = tid >> 3;
    const int tcol = (tid & 7) * 8;
    const u16* ga = A  + (size_t)(m0 + trow) * K + tcol;
    const u16* gb = Bt + (size_t)(n0 + trow) * K + tcol;

    auto stage = [&](int buf, int k0) {
        u16* la = As[buf] + tid * 8;
        u16* lb = Bs[buf] + tid * 8;
        #pragma unroll
        for (int p = 0; p < 4; ++p)
            gll16(ga + k0 + (size_t)p * 32 * K, la + p * 2048);
        #pragma unroll
        for (int p = 0; p < NJ; ++p)
            gll16(gb + k0 + (size_t)p * 32 * K, lb + p * 2048);
    };

    f32x4 acc[4][NJ] = {};

    const int fr = lane & 15;
    const int fk = (lane >> 4) * 8;

    const int nt = K >> 6;
    stage(0, 0);
    for (int t = 0; t < nt; ++t) {
        asm volatile("s_waitcnt vmcnt(0)" ::: "memory");
        __syncthreads();
        if (t + 1 < nt) stage((t + 1) & 1, (t + 1) << 6);

        const u16* as = As[t & 1];
        const u16* bs = Bs[t & 1];
        #pragma unroll
        for (int ks = 0; ks < 2; ++ks) {
            short8 af[4], bfr[NJ];
            #pragma unroll
            for (int f = 0; f < 4; ++f)
                af[f]  = *(const short8*)&as[(wr * 64 + f * 16 + fr) * 64 + ks * 32 + fk];
            #pragma unroll
            for (int f = 0; f < NJ; ++f)
                bfr[f] = *(const short8*)&bs[(wc * (BN / 2) + f * 16 + fr) * 64 + ks * 32 + fk];
            #pragma unroll
            for (int i = 0; i < 4; ++i)
                #pragma unroll
                for (int j = 0; j < NJ; ++j)
                    acc[i][j] = __builtin_amdgcn_mfma_f32_16x16x32_bf16(
                        af[i], bfr[j], acc[i][j], 0, 0, 0);
        }
    }

    const int c0 = n0 + wc * (BN / 2) + fr;
    const int r0 = m0 + wr * 64 + ((lane >> 4) << 2);
    #pragma unroll
    for (int j = 0; j < NJ; ++j) {
        const int c = c0 + j * 16;
        const float bv = bias ? bias[c] : 0.0f;
        #pragma unroll
        for (int i = 0; i < 4; ++i) {
            const int row0 = r0 + i * 16;
            if constexpr (QKV_SPLIT) {
                if (c < 1024) {
                    #pragma unroll
                    for (int r = 0; r < 4; ++r)
                        ((u16*)Cout)[(size_t)(row0 + r) * 1024 + c] =
                            f2bf_bits(acc[i][j][r] + bv);
                } else {
                    // vtb[(b*512 + (c-1024))*T + t], rows r -> t contiguous
                    ushort4 o;
                    o.x = f2bf_bits(acc[i][j][0] + bv);
                    o.y = f2bf_bits(acc[i][j][1] + bv);
                    o.z = f2bf_bits(acc[i][j][2] + bv);
                    o.w = f2bf_bits(acc[i][j][3] + bv);
                    const int t0 = row0 & (TT - 1);
                    *(ushort4*)&Vout[(((size_t)(row0 >> 11) * 512 + (c - 1024)) << 11) + t0] = o;
                }
            } else {
                #pragma unroll
                for (int r = 0; r < 4; ++r) {
                    const int row = row0 + r;
                    float v = acc[i][j][r] + bv;
                    if constexpr (GELU_ACT) v = gelu_exact(v);
                    if constexpr (RESID) v += resid[(size_t)row * N + c];
                    if constexpr (OUTBF16)
                        ((u16*)Cout)[(size_t)row * N + c] = f2bf_bits(v);
                    else
                        ((float*)Cout)[(size_t)row * N + c] = v;
                }
            }
        }
    }
}

// ---------------------------------------------------------------------------
// bf16 MFMA flash attention, double-buffered K/V + issue-early reg staging.
// Softmax: exp2 domain (scale*log2e folded), per-lane partial row-sums with
// the cross-lane reduce deferred to the epilogue; Q fragments hoisted.
// qkb: bf16 [M,1024] (q at +0, k at +512); vtb: bf16 [B][512][T].
// ---------------------------------------------------------------------------
__global__ __launch_bounds__(256)
void attn_kernel(const u16* __restrict__ qkb, const u16* __restrict__ vtb,
                 u16* __restrict__ y)
{
    const int l = blockIdx.x;
    const int u = l & 255, v = l >> 8;
    const int bh = u & 15;
    const int half = u >> 4;
    const int qt = v ? (16 + half) : (15 - half);
    const int h = bh & (HH - 1);
    const int b = bh >> 3;

    __shared__ alignas(16) u16 Qs[4096];
    __shared__ alignas(16) u16 Ks[2][4096];
    __shared__ alignas(16) u16 Vt[2][4096];   // [d][kv]
    __shared__ alignas(16) u16 Ps[4096];

    const int tid = threadIdx.x;
    const int lane = tid & 63;
    const int w = tid >> 6;
    const int ln = lane & 15, hi = lane >> 4;
    const int q0 = qt * 64;

    const u16* base  = qkb + (size_t)b * TT * 1024 + h * HD;
    const u16* vbase = vtb + (size_t)(b * 512 + h * HD) * TT;

    const int sr = tid >> 2, sc = (tid & 3) * 16;   // staging row/col

    // ---- stage Q (bf16, swizzled) + first K/V tile into regs ----
    {
        const u16* qrow = base + (size_t)(q0 + sr) * 1024;
        *(short8*)swp(Qs, sr, sc)     = *(const short8*)(qrow + sc);
        *(short8*)swp(Qs, sr, sc + 8) = *(const short8*)(qrow + sc + 8);
    }
    short8 rk0, rk1, rv0, rv1;
    {
        const u16* krow = base + (size_t)sr * 1024 + 512;
        rk0 = *(const short8*)(krow + sc);
        rk1 = *(const short8*)(krow + sc + 8);
        const u16* vrow = vbase + (size_t)sr * TT;
        rv0 = *(const short8*)(vrow + sc);
        rv1 = *(const short8*)(vrow + sc + 8);
    }
    __syncthreads();                               // Q visible

    // ---- hoist Q fragments (constant across k-tiles) ----
    short8 aq0 = *(const short8*)swpc(Qs, w * 16 + ln, hi * 8);
    short8 aq1 = *(const short8*)swpc(Qs, w * 16 + ln, 32 + hi * 8);

    const float SC = 0.18033688011112042f;         // 0.125 * log2(e)

    float m[4], lsum[4];
    f32x4 oacc[4] = {};
    #pragma unroll
    for (int r = 0; r < 4; ++r) { m[r] = -INFINITY; lsum[r] = 0.0f; }

    for (int kt = 0; kt <= qt; ++kt) {
        u16* ks = Ks[kt & 1];
        u16* vt = Vt[kt & 1];

        // ---- write staged regs to LDS (vmcnt wait here is a tile old) ----
        *(short8*)swp(ks, sr, sc)     = rk0;
        *(short8*)swp(ks, sr, sc + 8) = rk1;
        *(short8*)swp(vt, sr, sc)     = rv0;
        *(short8*)swp(vt, sr, sc + 8) = rv1;
        __syncthreads();

        // ---- issue next tile's loads (fly during compute below) ----
        if (kt < qt) {
            const int k0n = (kt + 1) * 64;
            const u16* krow = base + (size_t)(k0n + sr) * 1024 + 512;
            rk0 = *(const short8*)(krow + sc);
            rk1 = *(const short8*)(krow + sc + 8);
            const u16* vrow = vbase + (size_t)sr * TT + k0n;
            rv0 = *(const short8*)(vrow + sc);
            rv1 = *(const short8*)(vrow + sc + 8);
        }

        // ---- S = Q K^T ----
        f32x4 sacc[4] = {};
        __builtin_amdgcn_s_setprio(1);
        #pragma unroll
        for (int j = 0; j < 4; ++j) {
            short8 bk0 = *(const short8*)swpc(ks, j * 16 + ln, hi * 8);
            short8 bk1 = *(const short8*)swpc(ks, j * 16 + ln, 32 + hi * 8);
            sacc[j] = __builtin_amdgcn_mfma_f32_16x16x32_bf16(aq0, bk0, sacc[j], 0, 0, 0);
            sacc[j] = __builtin_amdgcn_mfma_f32_16x16x32_bf16(aq1, bk1, sacc[j], 0, 0, 0);
        }
        __builtin_amdgcn_s_setprio(0);

        // ---- online softmax (exp2 domain, per-lane partial sums) ----
        const bool diag = (kt == qt);
        #pragma unroll
        for (int r = 0; r < 4; ++r) {
            const int qrow = w * 16 + hi * 4 + r;
            float sv[4];
            #pragma unroll
            for (int j = 0; j < 4; ++j) {
                float s = sacc[j][r] * SC;
                if (diag && (j * 16 + ln > qrow)) s = -INFINITY;
                sv[j] = s;
            }
            float rm = fmaxf(fmaxf(sv[0], sv[1]), fmaxf(sv[2], sv[3]));
            #pragma unroll
            for (int o = 1; o < 16; o <<= 1) rm = fmaxf(rm, __shfl_xor(rm, o));
            float mn = fmaxf(m[r], rm);
            float corr = exp2f(m[r] - mn);
            m[r] = mn;
            float p0 = exp2f(sv[0] - mn);
            float p1 = exp2f(sv[1] - mn);
            float p2 = exp2f(sv[2] - mn);
            float p3 = exp2f(sv[3] - mn);
            *swp(Ps, qrow, ln)      = f2bf_bits(p0);
            *swp(Ps, qrow, 16 + ln) = f2bf_bits(p1);
            *swp(Ps, qrow, 32 + ln) = f2bf_bits(p2);
            *swp(Ps, qrow, 48 + ln) = f2bf_bits(p3);
            lsum[r] = lsum[r] * corr + ((p0 + p1) + (p2 + p3));
            #pragma unroll
            for (int db = 0; db < 4; ++db) oacc[db][r] *= corr;
        }

        // ---- O += P V (Ps rows are wave-private; no barrier needed) ----
        short8 ap0 = *(const short8*)swpc(Ps, w * 16 + ln, hi * 8);
        short8 ap1 = *(const short8*)swpc(Ps, w * 16 + ln, 32 + hi * 8);
        __builtin_amdgcn_s_setprio(1);
        #pragma unroll
        for (int db = 0; db < 4; ++db) {
            short8 bv0 = *(const short8*)swpc(vt, db * 16 + ln, hi * 8);
            short8 bv1 = *(const short8*)swpc(vt, db * 16 + ln, 32 + hi * 8);
            oacc[db] = __builtin_amdgcn_mfma_f32_16x16x32_bf16(ap0, bv0, oacc[db], 0, 0, 0);
            oacc[db] = __builtin_amdgcn_mfma_f32_16x16x32_bf16(ap1, bv1, oacc[db], 0, 0, 0);
        }
        __builtin_amdgcn_s_setprio(0);
    }

    // ---- epilogue: deferred l-reduction + normalize ----
    #pragma unroll
    for (int r = 0; r < 4; ++r) {
        float lt = lsum[r];
        #pragma unroll
        for (int o = 1; o < 16; o <<= 1) lt += __shfl_xor(lt, o);
        const int q = q0 + w * 16 + hi * 4 + r;
        const float inv = 1.0f / lt;
        u16* yrow = y + (size_t)(b * TT + q) * DD + h * HD;
        #pragma unroll
        for (int db = 0; db < 4; ++db)
            yrow[db * 16 + ln] = f2bf_bits(oacc[db][r] * inv);
    }
}

// ---------------------------------------------------------------------------
// Host-side launch
// ---------------------------------------------------------------------------
extern "C" void kernel_launch(void* const* d_in, const int* in_sizes, int n_in,
                              void* d_out, int out_size, void* d_ws, size_t ws_size,
                              hipStream_t stream)
{
    const int*   idx    = (const int*)  d_in[0];
    const float* wte    = (const float*)d_in[1];
    const float* wpe    = (const float*)d_in[2];
    const float* ln1_g  = (const float*)d_in[3];
    const float* ln1_b  = (const float*)d_in[4];
    const float* qkv_w  = (const float*)d_in[5];
    const float* qkv_b  = (const float*)d_in[6];
    const float* proj_w = (const float*)d_in[7];
    const float* proj_b = (const float*)d_in[8];
    const float* ln2_g  = (const float*)d_in[9];
    const float* ln2_b  = (const float*)d_in[10];
    const float* fc1_w  = (const float*)d_in[11];
    const float* fc1_b  = (const float*)d_in[12];
    const float* fc2_w  = (const float*)d_in[13];
    const float* fc2_b  = (const float*)d_in[14];
    const float* lnf_g  = (const float*)d_in[15];
    const float* lnf_b  = (const float*)d_in[16];
    float* out = (float*)d_out;

    char* ws = (char*)d_ws;
    float* x    = (float*)(ws);                       // [M,D] fp32      8 MB
    u16*   h    = (u16*)(ws + ((size_t)8  << 20));    // [M,D] bf16      4 MB
    u16*   y    = (u16*)(ws + ((size_t)12 << 20));    // [M,D] bf16      4 MB
    u16*   qkb  = (u16*)(ws + ((size_t)16 << 20));    // [M,1024] bf16   8 MB
    u16*   vtb  = (u16*)(ws + ((size_t)24 << 20));    // [B,512,T] bf16  4 MB
    u16*   wqa  = (u16*)(ws + ((size_t)28 << 20));    // 6*[1536,512]    9.4 MB
    u16*   wpa  = (u16*)(ws + ((size_t)38 << 20));    // 6*[512,512]     3.2 MB
    u16*   w1a  = (u16*)(ws + ((size_t)42 << 20));    // 6*[2048,512]   12.6 MB
    u16*   w2a  = (u16*)(ws + ((size_t)55 << 20));    // 6*[512,2048]   12.6 MB
    u16*   ffb  = (u16*)(ws + ((size_t)68 << 20));    // [M,F] bf16     16.8 MB
    u16*   wteb = (u16*)(ws + ((size_t)85 << 20));    // [V,D] bf16     32.8 MB

    embed_kernel<<<MM, 128, 0, stream>>>(idx, wte, wpe, x);

    weight_prep_kernel<<<LL * 3072, 256, 0, stream>>>(
        qkv_w, proj_w, fc1_w, fc2_w, wqa, wpa, w1a, w2a);

    cvt_kernel<<<(VV * DD / 4 + 255) / 256, 256, 0, stream>>>(wte, wteb, VV * DD / 4);

    for (int l = 0; l < LL; ++l) {
        ln_kernel<<<MM, 256, 0, stream>>>(x, ln1_g + l * DD, ln1_b + l * DD, h);

        mfma_gemm<128, false, false, true, true><<<dim3(12, 32), 256, 0, stream>>>(
            h, wqa + (size_t)l * 3 * DD * DD, qkv_b + (size_t)l * 3 * DD,
            nullptr, qkb, vtb, MM, 3 * DD, DD);

        attn_kernel<<<512, 256, 0, stream>>>(qkb, vtb, y);

        mfma_gemm<64, false, true, false, false><<<dim3(8, 32), 256, 0, stream>>>(
            y, wpa + (size_t)l * DD * DD, proj_b + (size_t)l * DD,
            x, x, nullptr, MM, DD, DD);

        ln_kernel<<<MM, 256, 0, stream>>>(x, ln2_g + l * DD, ln2_b + l * DD, h);

        mfma_gemm<128, true, false, true, false><<<dim3(16, 32), 256, 0, stream>>>(
            h, w1a + (size_t)l * DD * FF, fc1_b + (size_t)l * FF,
            nullptr, ffb, nullptr, MM, FF, DD);

        mfma_gemm<64, false, true, false, false><<<dim3(8, 32), 256, 0, stream>>>(
            ffb, w2a + (size_t)l * FF * DD, fc2_b + (size_t)l * DD,
            x, x, nullptr, MM, DD, FF);
    }

    ln_kernel<<<MM, 256, 0, stream>>>(x, lnf_g, lnf_b, h);

    mfma_gemm<128, false, false, false, false><<<dim3(250, 32), 256, 0, stream>>>(
        h, wteb, nullptr, nullptr, out, nullptr, MM, VV, DD);
}